// Round 1
// baseline (764.801 us; speedup 1.0000x reference)
//
#include <hip/hip_runtime.h>
#include <stdint.h>

#define T_ 4
#define B_ 32
#define N_ 256
#define C_ 384
#define H_ 8
#define D_ 48
#define ROWS (B_*N_)                  // 8192 (b,n) rows
#define SCALE_F 0.051031036307982884f // 384^-0.5

// workspace layout (bytes); all spike tensors stored as bf16 (exact for {0,1})
#define QS_OFF 0u                     // [T,B,H,D,N] bf16
#define KS_OFF 25165824u              // [T,B,H,D,N] bf16
#define VS_OFF 50331648u              // [T,B,H,N,D] bf16
#define AS_OFF 75497472u              // [T*B*N, C] bf16 (attn spikes, proj input)

__device__ __forceinline__ float bf16lo(uint32_t u){ return __uint_as_float(u << 16); }
__device__ __forceinline__ float bf16hi(uint32_t u){ return __uint_as_float(u & 0xffff0000u); }

// ---------------------------------------------------------------------------
// K1: fused  y = BN(x @ w^T) ; spikes = LIF_t(y)  for q/k/v (blockIdx.z picks branch)
// block: 256 thr; tile 64 (b,n)-rows x 64 cols x 4t; thread: 4t x 2r x 8c = 64 accs
// ---------------------------------------------------------------------------
__global__ __launch_bounds__(256, 3) void k_qkv(
    const float* __restrict__ x,
    const float* __restrict__ wq, const float* __restrict__ wk, const float* __restrict__ wv,
    const float* __restrict__ bnq, const float* __restrict__ bnk, const float* __restrict__ bnv,
    uint16_t* __restrict__ qs, uint16_t* __restrict__ ks, uint16_t* __restrict__ vs)
{
    const int br = blockIdx.z;
    const float* __restrict__ w  = (br==0)? wq : (br==1)? wk : wv;
    const float* __restrict__ bn = (br==0)? bnq: (br==1)? bnk: bnv;
    uint16_t* __restrict__ outp  = (br==0)? qs : (br==1)? ks : vs;
    const int r0 = blockIdx.x * 64;
    const int c0 = blockIdx.y * 64;
    __shared__ float Xs[4][32][66];   // [t][kk][row], pad 66: b64 reads aligned, 2-way max
    __shared__ float Ws[32][68];      // [kk][c], pad 68: b128 reads aligned
    const int tid = threadIdx.x;
    const int rp = tid & 31;          // rows 2rp, 2rp+1
    const int cg = tid >> 5;          // cols c0+cg*8 .. +7

    float acc[4][2][8];
    #pragma unroll
    for (int t=0;t<4;++t)
        #pragma unroll
        for (int r=0;r<2;++r)
            #pragma unroll
            for (int j=0;j<8;++j) acc[t][r][j]=0.f;

    for (int kt=0; kt<12; ++kt) {
        const int k0 = kt*32;
        __syncthreads();
        #pragma unroll
        for (int l = tid; l < 2048; l += 256) {          // X tile: 2048 float4
            const int kk4 = l & 7, row = (l>>3)&63, t = l>>9;
            const float4 v4 = *(const float4*)(x + ((size_t)(t*ROWS + r0 + row))*C_ + k0 + kk4*4);
            Xs[t][kk4*4+0][row]=v4.x; Xs[t][kk4*4+1][row]=v4.y;
            Xs[t][kk4*4+2][row]=v4.z; Xs[t][kk4*4+3][row]=v4.w;
        }
        #pragma unroll
        for (int l = tid; l < 512; l += 256) {           // W tile: 512 float4
            const int kk4 = l & 7, c = l>>3;
            const float4 v4 = *(const float4*)(w + (size_t)(c0+c)*C_ + k0 + kk4*4);
            Ws[kk4*4+0][c]=v4.x; Ws[kk4*4+1][c]=v4.y; Ws[kk4*4+2][c]=v4.z; Ws[kk4*4+3][c]=v4.w;
        }
        __syncthreads();
        #pragma unroll 8
        for (int kk=0; kk<32; ++kk) {
            const float2 xv0 = *(const float2*)&Xs[0][kk][2*rp];
            const float2 xv1 = *(const float2*)&Xs[1][kk][2*rp];
            const float2 xv2 = *(const float2*)&Xs[2][kk][2*rp];
            const float2 xv3 = *(const float2*)&Xs[3][kk][2*rp];
            float wv[8];
            *(float4*)&wv[0] = *(const float4*)&Ws[kk][cg*8];
            *(float4*)&wv[4] = *(const float4*)&Ws[kk][cg*8+4];
            #pragma unroll
            for (int j=0;j<8;++j) {
                acc[0][0][j] += xv0.x*wv[j]; acc[0][1][j] += xv0.y*wv[j];
                acc[1][0][j] += xv1.x*wv[j]; acc[1][1][j] += xv1.y*wv[j];
                acc[2][0][j] += xv2.x*wv[j]; acc[2][1][j] += xv2.y*wv[j];
                acc[3][0][j] += xv3.x*wv[j]; acc[3][1][j] += xv3.y*wv[j];
            }
        }
    }
    // epilogue: BN (reference op order, correctly-rounded rsqrt) + LIF over t + bf16 spike store
    float scl[8], mu[8], bet[8];
    #pragma unroll
    for (int j=0;j<8;++j) {
        const int c = c0 + cg*8 + j;
        const float g = bn[c], be = bn[C_+c], m = bn[2*C_+c], va = bn[3*C_+c];
        const float vp = va + 1e-5f;
        scl[j] = g * (float)(1.0 / sqrt((double)vp));
        mu[j] = m; bet[j] = be;
    }
    #pragma unroll
    for (int rr=0; rr<2; ++rr) {
        const int r = r0 + 2*rp + rr;
        const int b = r >> 8, n = r & 255;
        #pragma unroll
        for (int j=0;j<8;++j) {
            const int c = c0 + cg*8 + j;
            const int h = c / 48, d = c - h*48;
            float v = 0.f;
            #pragma unroll
            for (int t=0;t<4;++t) {
                const float y  = (acc[t][rr][j] - mu[j])*scl[j] + bet[j];
                const float hh = v + (y - v)*0.5f;                 // tau=2, reference form
                const uint16_t sp = (hh >= 1.0f) ? (uint16_t)0x3f80 : (uint16_t)0;
                v = (hh >= 1.0f) ? 0.f : hh;                       // hard reset, exact
                size_t addr;
                if (br == 2) addr = ((size_t)(((t*B_+b)*H_+h)*N_ + n))*D_ + d;  // v: [T,B,H,N,D]
                else         addr = ((size_t)(((t*B_+b)*H_+h)*D_ + d))*N_ + n;  // q,k: [T,B,H,D,N]
                outp[addr] = sp;
            }
        }
    }
}

// ---------------------------------------------------------------------------
// K2: fused attention + attn-LIF per (b,h,i-tile-128). 4 t sequential in-block
// (LIF state in regs). S = q.k^T exact integers; bias add bitwise == reference.
// LDS <= 64KB static. j-chunks of 64 (4 chunks), PV j-split-2.
// ---------------------------------------------------------------------------
__global__ __launch_bounds__(256, 2) void k_attn(
    const uint16_t* __restrict__ qs, const uint16_t* __restrict__ ks, const uint16_t* __restrict__ vs,
    const float* __restrict__ rel, uint16_t* __restrict__ as_)
{
    const int bh = blockIdx.x;
    const int b = bh >> 3, h = bh & 7;
    const int it = blockIdx.y;
    const int i0 = it * 128;
    __shared__ uint16_t qT[48][136];  // [d][i], bf16, 16B-aligned rows
    __shared__ uint16_t kT[48][72];   // [d][j-chunk]
    __shared__ uint16_t vvb[64][56];  // [j-chunk][d]
    __shared__ float    ST[64][132];  // [j][i] f32 scores(+bias); reused as reduction buf
    __shared__ float    bias_s[384];
    const int tid = threadIdx.x;
    const int ig = tid & 15, jg = tid >> 4;          // S-phase: rows ig*8.., cols jg*4..
    const int jhalf = tid >> 7, tl = tid & 127;      // PV phase
    const int ig2 = tl >> 3, dg = tl & 7;            // PV tile: 8i x 6d

    for (int l = tid; l < 383; l += 256)             // bias[i-j+255] window for this (h, i-tile)
        bias_s[l] = rel[(size_t)(i0 + l)*H_ + h];

    float vst[8][6];
    #pragma unroll
    for (int a=0;a<8;++a)
        #pragma unroll
        for (int e=0;e<6;++e) vst[a][e]=0.f;

    for (int t=0;t<4;++t) {
        const size_t base = ((size_t)((t*B_+b)*H_+h))*12288;   // 48*256
        __syncthreads();
        #pragma unroll
        for (int rep=0; rep<3; ++rep) {                        // qT: 768 uint4
            const int l = rep*256 + tid;
            const int d = l >> 4, seg = l & 15;
            *(uint4*)&qT[d][seg*8] = *(const uint4*)(qs + base + (size_t)d*N_ + i0 + seg*8);
        }
        float pv[8][6];
        #pragma unroll
        for (int a=0;a<8;++a)
            #pragma unroll
            for (int e=0;e<6;++e) pv[a][e]=0.f;

        for (int cch=0; cch<4; ++cch) {
            const int j0 = cch*64;
            __syncthreads();                                   // prev PV done; qT ready (cch=0)
            {   // kT: 384 uint4
                int l = tid;
                { const int d = l>>3, seg = l&7;
                  *(uint4*)&kT[d][seg*8] = *(const uint4*)(ks + base + (size_t)d*N_ + j0 + seg*8); }
                l = 256 + tid;
                if (l < 384) { const int d = l>>3, seg = l&7;
                  *(uint4*)&kT[d][seg*8] = *(const uint4*)(ks + base + (size_t)d*N_ + j0 + seg*8); }
            }
            {   // vvb: 384 uint4
                int l = tid;
                { const int j = l/6, seg = l - 6*(l/6);
                  *(uint4*)&vvb[j][seg*8] = *(const uint4*)(vs + base + (size_t)(j0 + j)*D_ + seg*8); }
                l = 256 + tid;
                if (l < 384) { const int j = l/6, seg = l - 6*(l/6);
                  *(uint4*)&vvb[j][seg*8] = *(const uint4*)(vs + base + (size_t)(j0 + j)*D_ + seg*8); }
            }
            __syncthreads();
            // S: [128i x 64j], thread tile 8i x 4j, exact integer sums
            float sa[8][4];
            #pragma unroll
            for (int a=0;a<8;++a)
                #pragma unroll
                for (int bb=0;bb<4;++bb) sa[a][bb]=0.f;
            #pragma unroll 4
            for (int d=0; d<48; ++d) {
                const uint4 qv = *(const uint4*)&qT[d][ig*8];
                const uint2 kv = *(const uint2*)&kT[d][jg*4];
                float qq[8], kk2[4];
                qq[0]=bf16lo(qv.x); qq[1]=bf16hi(qv.x); qq[2]=bf16lo(qv.y); qq[3]=bf16hi(qv.y);
                qq[4]=bf16lo(qv.z); qq[5]=bf16hi(qv.z); qq[6]=bf16lo(qv.w); qq[7]=bf16hi(qv.w);
                kk2[0]=bf16lo(kv.x); kk2[1]=bf16hi(kv.x); kk2[2]=bf16lo(kv.y); kk2[3]=bf16hi(kv.y);
                #pragma unroll
                for (int a=0;a<8;++a)
                    #pragma unroll
                    for (int bb=0;bb<4;++bb) sa[a][bb] += qq[a]*kk2[bb];
            }
            // ST[j][i] = S + bias (transposed store for PV)
            #pragma unroll
            for (int bb=0; bb<4; ++bb) {
                const int j = jg*4 + bb;
                const int boff = 255 - j0 - j;
                float tmp[8];
                #pragma unroll
                for (int a=0;a<8;++a) tmp[a] = sa[a][bb] + bias_s[ig*8 + a + boff];
                *(float4*)&ST[j][ig*8]   = *(float4*)&tmp[0];
                *(float4*)&ST[j][ig*8+4] = *(float4*)&tmp[4];
            }
            __syncthreads();
            // PV: accumulate out[i,d] += sum_j ST[j][i]*v[j][d]; thread 8i x 6d, j split in 2
            #pragma unroll 2
            for (int jj=0; jj<32; ++jj) {
                const int j = jhalf*32 + jj;
                const float4 s1 = *(const float4*)&ST[j][ig2*8];
                const float4 s2 = *(const float4*)&ST[j][ig2*8+4];
                const uint32_t* vp = (const uint32_t*)&vvb[j][dg*6];
                const uint32_t u0 = vp[0], u1 = vp[1], u2 = vp[2];
                float vv6[6];
                vv6[0]=bf16lo(u0); vv6[1]=bf16hi(u0); vv6[2]=bf16lo(u1);
                vv6[3]=bf16hi(u1); vv6[4]=bf16lo(u2); vv6[5]=bf16hi(u2);
                const float ss[8] = {s1.x,s1.y,s1.z,s1.w,s2.x,s2.y,s2.z,s2.w};
                #pragma unroll
                for (int a=0;a<8;++a)
                    #pragma unroll
                    for (int e=0;e<6;++e) pv[a][e] += ss[a]*vv6[e];
            }
        }
        __syncthreads();                                   // PV done; ST free -> reduction buffer
        float* red = (float*)&ST[0][0];
        if (jhalf == 1) {
            #pragma unroll
            for (int a=0;a<8;++a)
                #pragma unroll
                for (int e=0;e<6;++e) red[(ig2*8+a)*48 + dg*6+e] = pv[a][e];
        }
        __syncthreads();
        if (jhalf == 0) {
            #pragma unroll
            for (int a=0;a<8;++a) {
                const int n = i0 + ig2*8 + a;
                #pragma unroll
                for (int e=0;e<6;++e) {
                    const int d = dg*6 + e;
                    const float xin = (pv[a][e] + red[(ig2*8+a)*48 + d]) * SCALE_F;
                    const float hh = vst[a][e] + (xin - vst[a][e])*0.5f;
                    const uint16_t sp = (hh >= 1.0f) ? (uint16_t)0x3f80 : (uint16_t)0;
                    vst[a][e] = (hh >= 1.0f) ? 0.f : hh;
                    as_[((size_t)((t*B_+b)*N_ + n))*C_ + h*D_ + d] = sp;
                }
            }
        }
    }
}

// ---------------------------------------------------------------------------
// K3: proj  y = BN(spikes @ wp^T) ; out = LIF_t(y)  (f32 {0,1} -> d_out)
// same structure as K1; input spikes bf16 (exact), vectorized f32 output
// ---------------------------------------------------------------------------
__global__ __launch_bounds__(256, 3) void k_proj(
    const uint16_t* __restrict__ as_, const float* __restrict__ wp, const float* __restrict__ bnp,
    float* __restrict__ out)
{
    const int r0 = blockIdx.x * 64;
    const int c0 = blockIdx.y * 64;
    __shared__ float Xs[4][32][66];
    __shared__ float Ws[32][68];
    const int tid = threadIdx.x;
    const int rp = tid & 31, cg = tid >> 5;
    float acc[4][2][8];
    #pragma unroll
    for (int t=0;t<4;++t)
        #pragma unroll
        for (int r=0;r<2;++r)
            #pragma unroll
            for (int j=0;j<8;++j) acc[t][r][j]=0.f;

    for (int kt=0; kt<12; ++kt) {
        const int k0 = kt*32;
        __syncthreads();
        #pragma unroll
        for (int l = tid; l < 2048; l += 256) {
            const int kk4 = l & 7, row = (l>>3)&63, t = l>>9;
            const uint2 u = *(const uint2*)(as_ + ((size_t)(t*ROWS + r0 + row))*C_ + k0 + kk4*4);
            Xs[t][kk4*4+0][row]=bf16lo(u.x); Xs[t][kk4*4+1][row]=bf16hi(u.x);
            Xs[t][kk4*4+2][row]=bf16lo(u.y); Xs[t][kk4*4+3][row]=bf16hi(u.y);
        }
        #pragma unroll
        for (int l = tid; l < 512; l += 256) {
            const int kk4 = l & 7, c = l>>3;
            const float4 v4 = *(const float4*)(wp + (size_t)(c0+c)*C_ + k0 + kk4*4);
            Ws[kk4*4+0][c]=v4.x; Ws[kk4*4+1][c]=v4.y; Ws[kk4*4+2][c]=v4.z; Ws[kk4*4+3][c]=v4.w;
        }
        __syncthreads();
        #pragma unroll 8
        for (int kk=0; kk<32; ++kk) {
            const float2 xv0 = *(const float2*)&Xs[0][kk][2*rp];
            const float2 xv1 = *(const float2*)&Xs[1][kk][2*rp];
            const float2 xv2 = *(const float2*)&Xs[2][kk][2*rp];
            const float2 xv3 = *(const float2*)&Xs[3][kk][2*rp];
            float wv[8];
            *(float4*)&wv[0] = *(const float4*)&Ws[kk][cg*8];
            *(float4*)&wv[4] = *(const float4*)&Ws[kk][cg*8+4];
            #pragma unroll
            for (int j=0;j<8;++j) {
                acc[0][0][j] += xv0.x*wv[j]; acc[0][1][j] += xv0.y*wv[j];
                acc[1][0][j] += xv1.x*wv[j]; acc[1][1][j] += xv1.y*wv[j];
                acc[2][0][j] += xv2.x*wv[j]; acc[2][1][j] += xv2.y*wv[j];
                acc[3][0][j] += xv3.x*wv[j]; acc[3][1][j] += xv3.y*wv[j];
            }
        }
    }
    float scl[8], mu[8], bet[8];
    #pragma unroll
    for (int j=0;j<8;++j) {
        const int c = c0 + cg*8 + j;
        const float g = bnp[c], be = bnp[C_+c], m = bnp[2*C_+c], va = bnp[3*C_+c];
        const float vp = va + 1e-5f;
        scl[j] = g * (float)(1.0 / sqrt((double)vp));
        mu[j] = m; bet[j] = be;
    }
    #pragma unroll
    for (int rr=0;rr<2;++rr)
        #pragma unroll
        for (int j=0;j<8;++j) {
            float v=0.f;
            #pragma unroll
            for (int t=0;t<4;++t){
                const float y  = (acc[t][rr][j]-mu[j])*scl[j]+bet[j];
                const float hh = v + (y - v)*0.5f;
                const float sp = (hh>=1.0f)?1.0f:0.f;
                v = (hh>=1.0f)?0.f:hh;
                acc[t][rr][j]=sp;
            }
        }
    #pragma unroll
    for (int t=0;t<4;++t)
        #pragma unroll
        for (int rr=0;rr<2;++rr) {
            const int r = r0 + 2*rp + rr;
            const float4 o1 = make_float4(acc[t][rr][0],acc[t][rr][1],acc[t][rr][2],acc[t][rr][3]);
            const float4 o2 = make_float4(acc[t][rr][4],acc[t][rr][5],acc[t][rr][6],acc[t][rr][7]);
            *(float4*)(out + ((size_t)(t*ROWS + r))*C_ + c0 + cg*8)     = o1;
            *(float4*)(out + ((size_t)(t*ROWS + r))*C_ + c0 + cg*8 + 4) = o2;
        }
}

extern "C" void kernel_launch(void* const* d_in, const int* in_sizes, int n_in,
                              void* d_out, int out_size, void* d_ws, size_t ws_size,
                              hipStream_t stream) {
    const float* x   = (const float*)d_in[0];
    const float* wq  = (const float*)d_in[1];
    const float* wk  = (const float*)d_in[2];
    const float* wv  = (const float*)d_in[3];
    const float* wp  = (const float*)d_in[4];
    const float* bnq = (const float*)d_in[5];
    const float* bnk = (const float*)d_in[6];
    const float* bnv = (const float*)d_in[7];
    const float* bnp = (const float*)d_in[8];
    const float* rel = (const float*)d_in[9];
    float* out = (float*)d_out;
    uint8_t* ws = (uint8_t*)d_ws;
    uint16_t* qs  = (uint16_t*)(ws + QS_OFF);
    uint16_t* ks  = (uint16_t*)(ws + KS_OFF);
    uint16_t* vs  = (uint16_t*)(ws + VS_OFF);
    uint16_t* as_ = (uint16_t*)(ws + AS_OFF);

    k_qkv <<<dim3(128, 6, 3), 256, 0, stream>>>(x, wq, wk, wv, bnq, bnk, bnv, qs, ks, vs);
    k_attn<<<dim3(256, 2),    256, 0, stream>>>(qs, ks, vs, rel, as_);
    k_proj<<<dim3(128, 6),    256, 0, stream>>>(as_, wp, bnp, out);
}

// Round 2
// 559.524 us; speedup vs baseline: 1.3669x; 1.3669x over previous
//
#include <hip/hip_runtime.h>
#include <stdint.h>

#define T_ 4
#define B_ 32
#define N_ 256
#define C_ 384
#define H_ 8
#define D_ 48
#define ROWS (B_*N_)                  // 8192 (b,n) rows
#define SCALE_F 0.051031036307982884f // 384^-0.5

// workspace layout (bytes); all spike tensors stored as bf16 (exact for {0,1})
#define QS_OFF 0u                     // [T,B,N,C] bf16 (q spikes; region reused by w-split planes after k_attn)
#define KS_OFF 25165824u              // [T,B,N,C] bf16
#define VS_OFF 50331648u              // [T,B,H,D,N] bf16
#define AS_OFF 75497472u              // [T*B*N, C] bf16 (attn spikes, proj input)
// w_p split planes live inside the qs region (qs dead after k_attn; same-stream ordering)
#define WH_OFF 0u
#define WM_OFF 294912u
#define WL_OFF 589824u

typedef __bf16 bf16x8 __attribute__((ext_vector_type(8)));
typedef float  f32x4  __attribute__((ext_vector_type(4)));

__device__ __forceinline__ float bf16lo(uint32_t u){ return __uint_as_float(u << 16); }
__device__ __forceinline__ float bf16hi(uint32_t u){ return __uint_as_float(u & 0xffff0000u); }

// exact 3-way bf16 truncation split: s == h+m+l exactly (24-bit mantissa = 8+8+8)
__device__ __forceinline__ void split3(float s, uint32_t& h, uint32_t& m, uint32_t& l) {
    uint32_t u  = __float_as_uint(s);
    uint32_t hu = u & 0xffff0000u;
    float r1 = s - __uint_as_float(hu);             // exact
    uint32_t u1 = __float_as_uint(r1);
    uint32_t mu = u1 & 0xffff0000u;
    float r2 = r1 - __uint_as_float(mu);            // exact, <=8 significant bits
    h = hu >> 16; m = mu >> 16; l = __float_as_uint(r2) >> 16;
}

// ---------------------------------------------------------------------------
// K1: fused  y = BN(x @ w^T) ; spikes = LIF_t(y)  for q/k/v (blockIdx.z picks branch)
// unchanged compute from round-1 (known-good); output layouts:
//   q,k -> [T,B,N,C] bf16 (vectorized store), v -> [T,B,H,D,N] bf16
// ---------------------------------------------------------------------------
__global__ __launch_bounds__(256, 3) void k_qkv(
    const float* __restrict__ x,
    const float* __restrict__ wq, const float* __restrict__ wk, const float* __restrict__ wv,
    const float* __restrict__ bnq, const float* __restrict__ bnk, const float* __restrict__ bnv,
    uint16_t* __restrict__ qs, uint16_t* __restrict__ ks, uint16_t* __restrict__ vs)
{
    const int br = blockIdx.z;
    const float* __restrict__ w  = (br==0)? wq : (br==1)? wk : wv;
    const float* __restrict__ bn = (br==0)? bnq: (br==1)? bnk: bnv;
    uint16_t* __restrict__ outp  = (br==0)? qs : (br==1)? ks : vs;
    const int r0 = blockIdx.x * 64;
    const int c0 = blockIdx.y * 64;
    __shared__ float Xs[4][32][66];
    __shared__ float Ws[32][68];
    const int tid = threadIdx.x;
    const int rp = tid & 31;
    const int cg = tid >> 5;

    float acc[4][2][8];
    #pragma unroll
    for (int t=0;t<4;++t)
        #pragma unroll
        for (int r=0;r<2;++r)
            #pragma unroll
            for (int j=0;j<8;++j) acc[t][r][j]=0.f;

    for (int kt=0; kt<12; ++kt) {
        const int k0 = kt*32;
        __syncthreads();
        #pragma unroll
        for (int l = tid; l < 2048; l += 256) {
            const int kk4 = l & 7, row = (l>>3)&63, t = l>>9;
            const float4 v4 = *(const float4*)(x + ((size_t)(t*ROWS + r0 + row))*C_ + k0 + kk4*4);
            Xs[t][kk4*4+0][row]=v4.x; Xs[t][kk4*4+1][row]=v4.y;
            Xs[t][kk4*4+2][row]=v4.z; Xs[t][kk4*4+3][row]=v4.w;
        }
        #pragma unroll
        for (int l = tid; l < 512; l += 256) {
            const int kk4 = l & 7, c = l>>3;
            const float4 v4 = *(const float4*)(w + (size_t)(c0+c)*C_ + k0 + kk4*4);
            Ws[kk4*4+0][c]=v4.x; Ws[kk4*4+1][c]=v4.y; Ws[kk4*4+2][c]=v4.z; Ws[kk4*4+3][c]=v4.w;
        }
        __syncthreads();
        #pragma unroll 8
        for (int kk=0; kk<32; ++kk) {
            const float2 xv0 = *(const float2*)&Xs[0][kk][2*rp];
            const float2 xv1 = *(const float2*)&Xs[1][kk][2*rp];
            const float2 xv2 = *(const float2*)&Xs[2][kk][2*rp];
            const float2 xv3 = *(const float2*)&Xs[3][kk][2*rp];
            float wv[8];
            *(float4*)&wv[0] = *(const float4*)&Ws[kk][cg*8];
            *(float4*)&wv[4] = *(const float4*)&Ws[kk][cg*8+4];
            #pragma unroll
            for (int j=0;j<8;++j) {
                acc[0][0][j] += xv0.x*wv[j]; acc[0][1][j] += xv0.y*wv[j];
                acc[1][0][j] += xv1.x*wv[j]; acc[1][1][j] += xv1.y*wv[j];
                acc[2][0][j] += xv2.x*wv[j]; acc[2][1][j] += xv2.y*wv[j];
                acc[3][0][j] += xv3.x*wv[j]; acc[3][1][j] += xv3.y*wv[j];
            }
        }
    }
    float scl[8], mu[8], bet[8];
    #pragma unroll
    for (int j=0;j<8;++j) {
        const int c = c0 + cg*8 + j;
        const float g = bn[c], be = bn[C_+c], m = bn[2*C_+c], va = bn[3*C_+c];
        const float vp = va + 1e-5f;
        scl[j] = g * (float)(1.0 / sqrt((double)vp));
        mu[j] = m; bet[j] = be;
    }
    if (br == 2) {
        // v: [T,B,H,D,N]
        #pragma unroll
        for (int rr=0; rr<2; ++rr) {
            const int r = r0 + 2*rp + rr;
            const int b = r >> 8, n = r & 255;
            #pragma unroll
            for (int j=0;j<8;++j) {
                const int c = c0 + cg*8 + j;
                const int h = c / 48, d = c - h*48;
                float v = 0.f;
                #pragma unroll
                for (int t=0;t<4;++t) {
                    const float y  = (acc[t][rr][j] - mu[j])*scl[j] + bet[j];
                    const float hh = v + (y - v)*0.5f;
                    const uint16_t sp = (hh >= 1.0f) ? (uint16_t)0x3f80 : (uint16_t)0;
                    v = (hh >= 1.0f) ? 0.f : hh;
                    outp[((size_t)(((t*B_+b)*H_+h)*D_ + d))*N_ + n] = sp;
                }
            }
        }
    } else {
        // q,k: [T,B,N,C], vectorized 8-wide spike store
        #pragma unroll
        for (int rr=0; rr<2; ++rr) {
            const int r = r0 + 2*rp + rr;
            uint32_t wd[4][4];
            #pragma unroll
            for (int j=0;j<8;++j) {
                float v = 0.f;
                #pragma unroll
                for (int t=0;t<4;++t) {
                    const float y  = (acc[t][rr][j] - mu[j])*scl[j] + bet[j];
                    const float hh = v + (y - v)*0.5f;
                    const uint32_t sp = (hh >= 1.0f) ? 0x3f80u : 0u;
                    v = (hh >= 1.0f) ? 0.f : hh;
                    if (j & 1) wd[t][j>>1] |= sp << 16; else wd[t][j>>1] = sp;
                }
            }
            #pragma unroll
            for (int t=0;t<4;++t) {
                uint4 u4; u4.x = wd[t][0]; u4.y = wd[t][1]; u4.z = wd[t][2]; u4.w = wd[t][3];
                *(uint4*)&outp[((size_t)(t*ROWS + r))*C_ + c0 + cg*8] = u4;
            }
        }
    }
}

// ---------------------------------------------------------------------------
// K2: MFMA attention + attn-LIF. Block = (b,h, i-half of 128), 256 thr = 4 waves.
// S = q.k^T exact (binary bf16, integer sums); S+bias split EXACTLY into 3 bf16
// planes; PV = 3 bf16 MFMAs vs binary v. LIF state in regs across t.
// ---------------------------------------------------------------------------
__global__ __launch_bounds__(256, 2) void k_attn(
    const uint16_t* __restrict__ qs, const uint16_t* __restrict__ ks, const uint16_t* __restrict__ vs,
    const float* __restrict__ rel, uint16_t* __restrict__ as_)
{
    const int bh = blockIdx.x;
    const int b = bh >> 3, h = bh & 7;
    const int i0 = blockIdx.y * 128;

    __shared__ __align__(16) uint16_t qt[128][72];   // [i][d(0..63 used)] pad->36dw stride
    __shared__ __align__(16) uint16_t kt[32][72];    // [j][d]
    __shared__ __align__(16) uint16_t vT[48][40];    // [d][j] pad->20dw stride
    __shared__ __align__(16) uint16_t sh[3][128][40];// h/m/l planes [i][j], 20dw stride
    __shared__ float tab_s[384];                     // bias window rel[i0 .. i0+382]

    const int tid  = threadIdx.x;
    const int wv_  = tid >> 6;          // wave 0..3
    const int lane = tid & 63;
    const int l15  = lane & 15;
    const int quad = lane >> 4;
    const int w32  = wv_ * 32;          // wave's i-range base (32 rows)
    const int q8   = quad * 8;

    // bias window + LDS zero-padding (d=48..63) — once per block
    for (int l = tid; l < 383; l += 256) tab_s[l] = rel[(size_t)(i0 + l)*H_ + h];
    {
        const uint4 z = make_uint4(0,0,0,0);
        { const int row = tid >> 1, seg = tid & 1;          // 256 covers 128 rows x 2
          *(uint4*)&qt[row][48 + seg*8] = z; }
        if (tid < 64) { const int row = tid >> 1, seg = tid & 1;
          *(uint4*)&kt[row][48 + seg*8] = z; }
    }

    float vst[2][3][4];                  // LIF state: [i-tile][d-tile][reg]
    #pragma unroll
    for (int a=0;a<2;++a)
        #pragma unroll
        for (int e=0;e<3;++e)
            #pragma unroll
            for (int r=0;r<4;++r) vst[a][e][r]=0.f;

    for (int t=0; t<4; ++t) {
        const int tb = t*B_ + b;
        __syncthreads();                 // prev-t compute done before q restage
        // stage q tile: 128 rows x 48 d (bf16), 768 uint4
        #pragma unroll
        for (int rep=0; rep<3; ++rep) {
            const int l = rep*256 + tid;
            const int row = l / 6, seg = l - 6*row;
            *(uint4*)&qt[row][seg*8] =
                *(const uint4*)(qs + ((size_t)(tb*N_ + i0 + row))*C_ + h*D_ + seg*8);
        }

        f32x4 pacc[2][3];
        #pragma unroll
        for (int a=0;a<2;++a)
            #pragma unroll
            for (int e=0;e<3;++e) pacc[a][e] = (f32x4){0.f,0.f,0.f,0.f};

        for (int j0 = 0; j0 < 256; j0 += 32) {
            __syncthreads();             // protect kt/vT (and q on chunk 0)
            if (tid < 192) {             // stage k chunk: 32 rows x 48 d
                const int row = tid / 6, seg = tid - 6*row;
                *(uint4*)&kt[row][seg*8] =
                    *(const uint4*)(ks + ((size_t)(tb*N_ + j0 + row))*C_ + h*D_ + seg*8);
            } else {                     // stage vT chunk: 48 d-rows x 32 j
                const int l = tid - 192; // 0..63 of 192 total
                #pragma unroll
                for (int rep=0; rep<3; ++rep) {
                    const int e = rep*64 + l;
                    const int d = e >> 2, seg = e & 3;
                    *(uint4*)&vT[d][seg*8] =
                        *(const uint4*)(vs + (((size_t)(tb*H_ + h))*D_ + d)*N_ + j0 + seg*8);
                }
            }
            __syncthreads();

            // ---- QK: S tiles [2 i-tiles x 2 j-tiles], K = 64 (2 steps) ----
            f32x4 sacc[2][2];
            #pragma unroll
            for (int a=0;a<2;++a)
                #pragma unroll
                for (int c2=0;c2<2;++c2) sacc[a][c2] = (f32x4){0.f,0.f,0.f,0.f};
            bf16x8 qa[2][2];
            #pragma unroll
            for (int it=0; it<2; ++it)
                #pragma unroll
                for (int ks_=0; ks_<2; ++ks_)
                    qa[it][ks_] = *(const bf16x8*)&qt[w32 + it*16 + l15][ks_*32 + q8];
            #pragma unroll
            for (int jt=0; jt<2; ++jt) {
                #pragma unroll
                for (int ks_=0; ks_<2; ++ks_) {
                    const bf16x8 kb = *(const bf16x8*)&kt[jt*16 + l15][ks_*32 + q8];
                    #pragma unroll
                    for (int it=0; it<2; ++it)
                        sacc[it][jt] = __builtin_amdgcn_mfma_f32_16x16x32_bf16(
                            qa[it][ks_], kb, sacc[it][jt], 0, 0, 0);
                }
            }

            // ---- bias add + exact 3-way split -> sh planes (wave-private i rows) ----
            #pragma unroll
            for (int it=0; it<2; ++it)
                #pragma unroll
                for (int jt=0; jt<2; ++jt) {
                    const int jl = jt*16 + l15;
                    const int jg = j0 + jl;
                    #pragma unroll
                    for (int r=0; r<4; ++r) {
                        const int il = w32 + it*16 + quad*4 + r;
                        const float s = sacc[it][jt][r] + tab_s[il - jg + 255];
                        uint32_t hh, mm, ll;
                        split3(s, hh, mm, ll);
                        sh[0][il][jl] = (uint16_t)hh;
                        sh[1][il][jl] = (uint16_t)mm;
                        sh[2][il][jl] = (uint16_t)ll;
                    }
                }
            // no barrier needed: each wave reads only its own i-rows of sh;
            // in-wave LDS RAW ordering is handled by lgkmcnt.

            // ---- PV: out[i][d] += sum_j (h+m+l)[i][j] * v[j][d], K = 32 ----
            bf16x8 vb[3];
            #pragma unroll
            for (int dt=0; dt<3; ++dt)
                vb[dt] = *(const bf16x8*)&vT[dt*16 + l15][q8];
            #pragma unroll
            for (int it=0; it<2; ++it)
                #pragma unroll
                for (int p=0; p<3; ++p) {
                    const bf16x8 sa = *(const bf16x8*)&sh[p][w32 + it*16 + l15][q8];
                    #pragma unroll
                    for (int dt=0; dt<3; ++dt)
                        pacc[it][dt] = __builtin_amdgcn_mfma_f32_16x16x32_bf16(
                            sa, vb[dt], pacc[it][dt], 0, 0, 0);
                }
        }

        // ---- epilogue t: scale, LIF, spike store ----
        #pragma unroll
        for (int it=0; it<2; ++it)
            #pragma unroll
            for (int dt=0; dt<3; ++dt)
                #pragma unroll
                for (int r=0; r<4; ++r) {
                    const float xin = pacc[it][dt][r] * SCALE_F;
                    float v = vst[it][dt][r];
                    const float hh = v + (xin - v)*0.5f;
                    const uint16_t sp = (hh >= 1.0f) ? (uint16_t)0x3f80 : (uint16_t)0;
                    vst[it][dt][r] = (hh >= 1.0f) ? 0.f : hh;
                    const int ig = i0 + w32 + it*16 + quad*4 + r;
                    const int c  = h*D_ + dt*16 + l15;
                    as_[((size_t)(tb*N_ + ig))*C_ + c] = sp;
                }
    }
}

// ---------------------------------------------------------------------------
// K2.5: exact 3-way split of w_p into bf16 planes [c][k] (wh+wm+wl == w_p)
// ---------------------------------------------------------------------------
__global__ void k_wsplit(const float* __restrict__ wp,
                         uint16_t* __restrict__ wh, uint16_t* __restrict__ wm,
                         uint16_t* __restrict__ wl)
{
    const int idx = blockIdx.x*256 + threadIdx.x;   // 147456 elements
    uint32_t h, m, l;
    split3(wp[idx], h, m, l);
    wh[idx] = (uint16_t)h; wm[idx] = (uint16_t)m; wl[idx] = (uint16_t)l;
}

// ---------------------------------------------------------------------------
// K3: MFMA proj  y = BN(spikes @ wp^T) ; out = LIF_t(y)
// block tile: 64 (b,n)-rows x 4 t x 96 cols; wave: 16 rows x 4t x 6 n-tiles
// ---------------------------------------------------------------------------
__global__ __launch_bounds__(256, 2) void k_proj(
    const uint16_t* __restrict__ as_,
    const uint16_t* __restrict__ wh, const uint16_t* __restrict__ wm,
    const uint16_t* __restrict__ wl,
    const float* __restrict__ bnp, float* __restrict__ out)
{
    const int r0 = blockIdx.x * 64;     // (b,n)-row base
    const int c0 = blockIdx.y * 96;

    __shared__ __align__(16) uint16_t At[4][64][40];  // [t][row][k] 20dw stride
    __shared__ __align__(16) uint16_t Bt[3][96][40];  // [plane][c][k]

    const int tid  = threadIdx.x;
    const int wv_  = tid >> 6;
    const int lane = tid & 63;
    const int l15  = lane & 15;
    const int quad = lane >> 4;
    const int q8   = quad * 8;

    f32x4 acc[4][6];
    #pragma unroll
    for (int t=0;t<4;++t)
        #pragma unroll
        for (int nt=0;nt<6;++nt) acc[t][nt] = (f32x4){0.f,0.f,0.f,0.f};

    for (int kstep=0; kstep<12; ++kstep) {
        const int k0 = kstep*32;
        __syncthreads();
        // stage A: 4t x 64 rows x 32 k = 1024 uint4
        #pragma unroll
        for (int rep=0; rep<4; ++rep) {
            const int l = rep*256 + tid;
            const int t = l >> 8, row = (l >> 2) & 63, seg = l & 3;
            *(uint4*)&At[t][row][seg*8] =
                *(const uint4*)(as_ + ((size_t)(t*ROWS + r0 + row))*C_ + k0 + seg*8);
        }
        // stage B: 3 planes x 96 c x 32 k = 1152 uint4
        for (int l = tid; l < 1152; l += 256) {
            const int p = l / 384, rem = l - 384*p;
            const int c = rem >> 2, seg = rem & 3;
            const uint16_t* src = (p==0)? wh : (p==1)? wm : wl;
            *(uint4*)&Bt[p][c][seg*8] =
                *(const uint4*)(src + (size_t)(c0 + c)*C_ + k0 + seg*8);
        }
        __syncthreads();

        bf16x8 af[4];
        #pragma unroll
        for (int t=0;t<4;++t)
            af[t] = *(const bf16x8*)&At[t][wv_*16 + l15][q8];
        #pragma unroll
        for (int nt=0; nt<6; ++nt) {
            #pragma unroll
            for (int p=0; p<3; ++p) {
                const bf16x8 bf_ = *(const bf16x8*)&Bt[p][nt*16 + l15][q8];
                #pragma unroll
                for (int t=0;t<4;++t)
                    acc[t][nt] = __builtin_amdgcn_mfma_f32_16x16x32_bf16(
                        af[t], bf_, acc[t][nt], 0, 0, 0);
            }
        }
    }

    // epilogue: BN + LIF over t, f32 spike output
    #pragma unroll
    for (int nt=0; nt<6; ++nt) {
        const int c = c0 + nt*16 + l15;
        const float g = bnp[c], be = bnp[C_+c], mu = bnp[2*C_+c], va = bnp[3*C_+c];
        const float scl = g * (float)(1.0 / sqrt((double)(va + 1e-5f)));
        #pragma unroll
        for (int r=0; r<4; ++r) {
            const int rg = r0 + wv_*16 + quad*4 + r;
            float v = 0.f;
            #pragma unroll
            for (int t=0; t<4; ++t) {
                const float y  = (acc[t][nt][r] - mu)*scl + be;
                const float hh = v + (y - v)*0.5f;
                const float sp = (hh >= 1.0f) ? 1.0f : 0.f;
                v = (hh >= 1.0f) ? 0.f : hh;
                out[((size_t)(t*ROWS + rg))*C_ + c] = sp;
            }
        }
    }
}

extern "C" void kernel_launch(void* const* d_in, const int* in_sizes, int n_in,
                              void* d_out, int out_size, void* d_ws, size_t ws_size,
                              hipStream_t stream) {
    const float* x   = (const float*)d_in[0];
    const float* wq  = (const float*)d_in[1];
    const float* wk  = (const float*)d_in[2];
    const float* wv  = (const float*)d_in[3];
    const float* wp  = (const float*)d_in[4];
    const float* bnq = (const float*)d_in[5];
    const float* bnk = (const float*)d_in[6];
    const float* bnv = (const float*)d_in[7];
    const float* bnp = (const float*)d_in[8];
    const float* rel = (const float*)d_in[9];
    float* out = (float*)d_out;
    uint8_t* ws = (uint8_t*)d_ws;
    uint16_t* qs  = (uint16_t*)(ws + QS_OFF);
    uint16_t* ks  = (uint16_t*)(ws + KS_OFF);
    uint16_t* vs  = (uint16_t*)(ws + VS_OFF);
    uint16_t* as_ = (uint16_t*)(ws + AS_OFF);
    uint16_t* wh  = (uint16_t*)(ws + WH_OFF);
    uint16_t* wm  = (uint16_t*)(ws + WM_OFF);
    uint16_t* wl  = (uint16_t*)(ws + WL_OFF);

    k_qkv  <<<dim3(128, 6, 3), 256, 0, stream>>>(x, wq, wk, wv, bnq, bnk, bnv, qs, ks, vs);
    k_attn <<<dim3(256, 2),    256, 0, stream>>>(qs, ks, vs, rel, as_);
    k_wsplit<<<dim3(576),      256, 0, stream>>>(wp, wh, wm, wl);   // overwrites dead qs region
    k_proj <<<dim3(128, 4),    256, 0, stream>>>(as_, wh, wm, wl, bnp, out);
}

// Round 3
// 402.493 us; speedup vs baseline: 1.9002x; 1.3901x over previous
//
#include <hip/hip_runtime.h>
#include <stdint.h>

#define T_ 4
#define B_ 32
#define N_ 256
#define C_ 384
#define H_ 8
#define D_ 48
#define ROWS (B_*N_)                  // 8192 (b,n) rows
#define SCALE_F 0.051031036307982884f // 384^-0.5

// workspace layout (bytes); all spike tensors stored as bf16 (exact for {0,1})
#define QS_OFF 0u                     // [T,B,N,C] bf16 q spikes (region reused by wp-planes after k_attn)
#define KS_OFF 25165824u              // [T,B,N,C] bf16
#define VS_OFF 50331648u              // [T,B,H,D,N] bf16
#define AS_OFF 75497472u              // [T*B*N, C] bf16 attn spikes; head reused for w-branch planes BEFORE k_attn
// w_p split planes (for k_proj) live in the qs region (qs dead after k_attn)
#define WH_OFF 0u
#define WM_OFF 294912u
#define WL_OFF 589824u

typedef __bf16 bf16x8 __attribute__((ext_vector_type(8)));
typedef float  f32x4  __attribute__((ext_vector_type(4)));

// exact 3-way bf16 truncation split: s == h+m+l exactly (24-bit mantissa = 8+8+8)
__device__ __forceinline__ void split3(float s, uint32_t& h, uint32_t& m, uint32_t& l) {
    uint32_t u  = __float_as_uint(s);
    uint32_t hu = u & 0xffff0000u;
    float r1 = s - __uint_as_float(hu);             // exact
    uint32_t u1 = __float_as_uint(r1);
    uint32_t mu = u1 & 0xffff0000u;
    float r2 = r1 - __uint_as_float(mu);            // exact, <=8 significant bits
    h = hu >> 16; m = mu >> 16; l = __float_as_uint(r2) >> 16;
}

// ---------------------------------------------------------------------------
// K0: exact 3-way split of w_q/w_k/w_v into bf16 planes [branch][plane][c][k]
// written into the (currently dead) as_ region head
// ---------------------------------------------------------------------------
__global__ void k_wsplit3(const float* __restrict__ wq, const float* __restrict__ wk,
                          const float* __restrict__ wv, uint16_t* __restrict__ out)
{
    const int br = blockIdx.y;
    const float* __restrict__ w = (br==0)? wq : (br==1)? wk : wv;
    const int idx = blockIdx.x*256 + threadIdx.x;   // 147456 elements
    uint32_t h, m, l;
    split3(w[idx], h, m, l);
    uint16_t* base = out + (size_t)br*442368;
    base[idx] = (uint16_t)h;
    base[147456 + idx] = (uint16_t)m;
    base[294912 + idx] = (uint16_t)l;
}

// ---------------------------------------------------------------------------
// K1: MFMA qkv GEMM + BN + LIF.  y = BN(x @ w^T); spikes = LIF_t(y).
// x and w both split 3-way bf16 (exact); 6 MFMA products per acc (>= 2^-16
// terms kept; dropped terms ~2^-23 — measured-safe fp32-noise class).
// Block = 32 (b,n)-rows x 4 t (M=128, t-major) x 128 cols; 4 waves (2 rg x 2 cg),
// wave tile 64x64. LIF v-state crosses the t1->t2 wave boundary via LDS.
// ---------------------------------------------------------------------------
__global__ __launch_bounds__(256, 3) void k_qkv_mfma(
    const float* __restrict__ x, const uint16_t* __restrict__ wbr,
    const float* __restrict__ bnq, const float* __restrict__ bnk, const float* __restrict__ bnv,
    uint16_t* __restrict__ qs, uint16_t* __restrict__ ks, uint16_t* __restrict__ vs)
{
    const int cb = blockIdx.x;               // 0..8 (fastest -> 9 blocks share the A-strip in L2/L3)
    const int branch = cb / 3;
    const int ct = cb - branch*3;
    const int c0 = ct * 128;
    const int bn0 = blockIdx.y * 32;
    const float* __restrict__ bnp_ = (branch==0)? bnq : (branch==1)? bnk : bnv;
    uint16_t* __restrict__ outp = (branch==0)? qs : (branch==1)? ks : vs;
    const uint16_t* __restrict__ wpl = wbr + (size_t)branch*442368;

    // 104-elem rows (3 planes x 32k + 8 pad): 16B-aligned, spreads b128 accesses
    // over all 8 four-bank groups (optimal 8-pass)
    __shared__ __align__(16) uint16_t At[128][104];   // [t*32+bn][plane*32+k]
    __shared__ __align__(16) uint16_t Bt[128][104];   // [c][plane*32+k]

    const int tid  = threadIdx.x;
    const int wv   = tid >> 6;
    const int lane = tid & 63;
    const int l15  = lane & 15;
    const int quad = lane >> 4;
    const int q8   = quad * 8;
    const int rg   = wv >> 1;            // t-pair group: rg0 -> t0,t1 ; rg1 -> t2,t3
    const int wcol = (wv & 1) * 64;

    f32x4 acc[4][4];
    #pragma unroll
    for (int it=0; it<4; ++it)
        #pragma unroll
        for (int jt=0; jt<4; ++jt) acc[it][jt] = (f32x4){0.f,0.f,0.f,0.f};

    // A staging assignment: thread -> (trow = t*32+bnl, half of 32k)
    const int trow = tid >> 1, half = tid & 1;
    const int tA = trow >> 5, bnlA = trow & 31;
    const float* xrow = x + ((size_t)(tA*ROWS + bn0 + bnlA))*C_ + half*16;

    for (int kt=0; kt<12; ++kt) {
        const int k0 = kt*32;
        __syncthreads();
        {   // ---- A stage: load 16 fp32, split3, pack, write 3 planes ----
            float4 f0 = *(const float4*)(xrow + k0);
            float4 f1 = *(const float4*)(xrow + k0 + 4);
            float4 f2 = *(const float4*)(xrow + k0 + 8);
            float4 f3 = *(const float4*)(xrow + k0 + 12);
            float fe[16];
            *(float4*)&fe[0] = f0; *(float4*)&fe[4] = f1;
            *(float4*)&fe[8] = f2; *(float4*)&fe[12] = f3;
            uint32_t hw[8], mw[8], lw[8];
            #pragma unroll
            for (int i=0; i<8; ++i) {
                const float s0 = fe[2*i], s1 = fe[2*i+1];
                const uint32_t h0 = __float_as_uint(s0) & 0xffff0000u;
                const uint32_t h1 = __float_as_uint(s1) & 0xffff0000u;
                const float r0 = s0 - __uint_as_float(h0);
                const float r1 = s1 - __uint_as_float(h1);
                const uint32_t m0 = __float_as_uint(r0) & 0xffff0000u;
                const uint32_t m1 = __float_as_uint(r1) & 0xffff0000u;
                const float p0 = r0 - __uint_as_float(m0);
                const float p1 = r1 - __uint_as_float(m1);
                hw[i] = (h0>>16) | h1;
                mw[i] = (m0>>16) | m1;
                lw[i] = (__float_as_uint(p0)>>16) | (__float_as_uint(p1) & 0xffff0000u);
            }
            *(uint4*)&At[trow][ 0 + half*16]     = make_uint4(hw[0],hw[1],hw[2],hw[3]);
            *(uint4*)&At[trow][ 0 + half*16 + 8] = make_uint4(hw[4],hw[5],hw[6],hw[7]);
            *(uint4*)&At[trow][32 + half*16]     = make_uint4(mw[0],mw[1],mw[2],mw[3]);
            *(uint4*)&At[trow][32 + half*16 + 8] = make_uint4(mw[4],mw[5],mw[6],mw[7]);
            *(uint4*)&At[trow][64 + half*16]     = make_uint4(lw[0],lw[1],lw[2],lw[3]);
            *(uint4*)&At[trow][64 + half*16 + 8] = make_uint4(lw[4],lw[5],lw[6],lw[7]);
        }
        // ---- B stage: 3 planes x 128 c x 32 k = 1536 uint4 ----
        #pragma unroll
        for (int rep=0; rep<6; ++rep) {
            const int id = rep*256 + tid;
            const int p = id >> 9, rem = id & 511, c = rem >> 2, ks8 = rem & 3;
            *(uint4*)&Bt[c][p*32 + ks8*8] =
                *(const uint4*)(wpl + (size_t)p*147456 + (size_t)(c0 + c)*C_ + k0 + ks8*8);
        }
        __syncthreads();

        // ---- fragments + 6-product MFMA ----
        bf16x8 af[4][3];
        #pragma unroll
        for (int it=0; it<4; ++it) {
            const uint16_t* ar = &At[rg*64 + it*16 + l15][q8];
            af[it][0] = *(const bf16x8*)(ar);
            af[it][1] = *(const bf16x8*)(ar + 32);
            af[it][2] = *(const bf16x8*)(ar + 64);
        }
        #pragma unroll
        for (int jt=0; jt<4; ++jt) {
            const uint16_t* bb = &Bt[wcol + jt*16 + l15][q8];
            const bf16x8 b0 = *(const bf16x8*)(bb);
            const bf16x8 b1 = *(const bf16x8*)(bb + 32);
            const bf16x8 b2 = *(const bf16x8*)(bb + 64);
            #pragma unroll
            for (int it=0; it<4; ++it) {
                f32x4 a = acc[it][jt];
                a = __builtin_amdgcn_mfma_f32_16x16x32_bf16(af[it][0], b0, a, 0,0,0);
                a = __builtin_amdgcn_mfma_f32_16x16x32_bf16(af[it][0], b1, a, 0,0,0);
                a = __builtin_amdgcn_mfma_f32_16x16x32_bf16(af[it][1], b0, a, 0,0,0);
                a = __builtin_amdgcn_mfma_f32_16x16x32_bf16(af[it][0], b2, a, 0,0,0);
                a = __builtin_amdgcn_mfma_f32_16x16x32_bf16(af[it][1], b1, a, 0,0,0);
                a = __builtin_amdgcn_mfma_f32_16x16x32_bf16(af[it][2], b0, a, 0,0,0);
                acc[it][jt] = a;
            }
        }
    }

    // ---- epilogue: BN + LIF over t (t0,t1 in rg0 waves; t2,t3 in rg1) ----
    // acc tile mapping: M-row = rg*64 + it*16 + quad*4 + r = t*32 + bnl with
    // t = rg*2 + (it>>1), bnl = (it&1)*16 + quad*4 + r; col = wcol + jt*16 + l15.
    __syncthreads();                    // At dead -> reuse as v-state exchange
    float* vex = (float*)&At[0][0];     // vex[bnl*128 + col_local], 16 KB

    #define STORE_SP(tt, sp) do { \
        if (branch == 2) { \
            const int h2 = cg / 48, dd = cg - h2*48; \
            const int bng = bn0 + bnl; \
            outp[((((size_t)(tt)*B_ + (bng>>8))*H_ + h2)*D_ + dd)*N_ + (bng&255)] = (sp); \
        } else { \
            outp[((size_t)((tt)*ROWS + bn0 + bnl))*C_ + cg] = (sp); \
        } \
    } while(0)

    if (rg == 0) {
        #pragma unroll
        for (int jt=0; jt<4; ++jt) {
            const int cl = wcol + jt*16 + l15;
            const int cg = c0 + cl;
            const float g = bnp_[cg], be = bnp_[C_+cg], mu = bnp_[2*C_+cg], va = bnp_[3*C_+cg];
            const float scl = g * (float)(1.0 / sqrt((double)(va + 1e-5f)));
            #pragma unroll
            for (int a=0; a<2; ++a)
                #pragma unroll
                for (int r=0; r<4; ++r) {
                    const int bnl = a*16 + quad*4 + r;
                    const float y0 = (acc[a  ][jt][r] - mu)*scl + be;
                    const float y1 = (acc[a+2][jt][r] - mu)*scl + be;
                    float v = 0.f;
                    float h = v + (y0 - v)*0.5f;
                    STORE_SP(0, (h >= 1.0f) ? (uint16_t)0x3f80 : (uint16_t)0);
                    v = (h >= 1.0f) ? 0.f : h;
                    h = v + (y1 - v)*0.5f;
                    STORE_SP(1, (h >= 1.0f) ? (uint16_t)0x3f80 : (uint16_t)0);
                    v = (h >= 1.0f) ? 0.f : h;
                    vex[bnl*128 + cl] = v;
                }
        }
    }
    __syncthreads();
    if (rg == 1) {
        #pragma unroll
        for (int jt=0; jt<4; ++jt) {
            const int cl = wcol + jt*16 + l15;
            const int cg = c0 + cl;
            const float g = bnp_[cg], be = bnp_[C_+cg], mu = bnp_[2*C_+cg], va = bnp_[3*C_+cg];
            const float scl = g * (float)(1.0 / sqrt((double)(va + 1e-5f)));
            #pragma unroll
            for (int a=0; a<2; ++a)
                #pragma unroll
                for (int r=0; r<4; ++r) {
                    const int bnl = a*16 + quad*4 + r;
                    const float y2 = (acc[a  ][jt][r] - mu)*scl + be;
                    const float y3 = (acc[a+2][jt][r] - mu)*scl + be;
                    float v = vex[bnl*128 + cl];
                    float h = v + (y2 - v)*0.5f;
                    STORE_SP(2, (h >= 1.0f) ? (uint16_t)0x3f80 : (uint16_t)0);
                    v = (h >= 1.0f) ? 0.f : h;
                    h = v + (y3 - v)*0.5f;
                    STORE_SP(3, (h >= 1.0f) ? (uint16_t)0x3f80 : (uint16_t)0);
                }
        }
    }
    #undef STORE_SP
}

// ---------------------------------------------------------------------------
// K2: MFMA attention + attn-LIF (unchanged from round 2 — verified)
// ---------------------------------------------------------------------------
__global__ __launch_bounds__(256, 2) void k_attn(
    const uint16_t* __restrict__ qs, const uint16_t* __restrict__ ks, const uint16_t* __restrict__ vs,
    const float* __restrict__ rel, uint16_t* __restrict__ as_)
{
    const int bh = blockIdx.x;
    const int b = bh >> 3, h = bh & 7;
    const int i0 = blockIdx.y * 128;

    __shared__ __align__(16) uint16_t qt[128][72];
    __shared__ __align__(16) uint16_t kt[32][72];
    __shared__ __align__(16) uint16_t vT[48][40];
    __shared__ __align__(16) uint16_t sh[3][128][40];
    __shared__ float tab_s[384];

    const int tid  = threadIdx.x;
    const int wv_  = tid >> 6;
    const int lane = tid & 63;
    const int l15  = lane & 15;
    const int quad = lane >> 4;
    const int w32  = wv_ * 32;
    const int q8   = quad * 8;

    for (int l = tid; l < 383; l += 256) tab_s[l] = rel[(size_t)(i0 + l)*H_ + h];
    {
        const uint4 z = make_uint4(0,0,0,0);
        { const int row = tid >> 1, seg = tid & 1;
          *(uint4*)&qt[row][48 + seg*8] = z; }
        if (tid < 64) { const int row = tid >> 1, seg = tid & 1;
          *(uint4*)&kt[row][48 + seg*8] = z; }
    }

    float vst[2][3][4];
    #pragma unroll
    for (int a=0;a<2;++a)
        #pragma unroll
        for (int e=0;e<3;++e)
            #pragma unroll
            for (int r=0;r<4;++r) vst[a][e][r]=0.f;

    for (int t=0; t<4; ++t) {
        const int tb = t*B_ + b;
        __syncthreads();
        #pragma unroll
        for (int rep=0; rep<3; ++rep) {
            const int l = rep*256 + tid;
            const int row = l / 6, seg = l - 6*row;
            *(uint4*)&qt[row][seg*8] =
                *(const uint4*)(qs + ((size_t)(tb*N_ + i0 + row))*C_ + h*D_ + seg*8);
        }

        f32x4 pacc[2][3];
        #pragma unroll
        for (int a=0;a<2;++a)
            #pragma unroll
            for (int e=0;e<3;++e) pacc[a][e] = (f32x4){0.f,0.f,0.f,0.f};

        for (int j0 = 0; j0 < 256; j0 += 32) {
            __syncthreads();
            if (tid < 192) {
                const int row = tid / 6, seg = tid - 6*row;
                *(uint4*)&kt[row][seg*8] =
                    *(const uint4*)(ks + ((size_t)(tb*N_ + j0 + row))*C_ + h*D_ + seg*8);
            } else {
                const int l = tid - 192;
                #pragma unroll
                for (int rep=0; rep<3; ++rep) {
                    const int e = rep*64 + l;
                    const int d = e >> 2, seg = e & 3;
                    *(uint4*)&vT[d][seg*8] =
                        *(const uint4*)(vs + (((size_t)(tb*H_ + h))*D_ + d)*N_ + j0 + seg*8);
                }
            }
            __syncthreads();

            f32x4 sacc[2][2];
            #pragma unroll
            for (int a=0;a<2;++a)
                #pragma unroll
                for (int c2=0;c2<2;++c2) sacc[a][c2] = (f32x4){0.f,0.f,0.f,0.f};
            bf16x8 qa[2][2];
            #pragma unroll
            for (int it=0; it<2; ++it)
                #pragma unroll
                for (int ks_=0; ks_<2; ++ks_)
                    qa[it][ks_] = *(const bf16x8*)&qt[w32 + it*16 + l15][ks_*32 + q8];
            #pragma unroll
            for (int jt=0; jt<2; ++jt) {
                #pragma unroll
                for (int ks_=0; ks_<2; ++ks_) {
                    const bf16x8 kb = *(const bf16x8*)&kt[jt*16 + l15][ks_*32 + q8];
                    #pragma unroll
                    for (int it=0; it<2; ++it)
                        sacc[it][jt] = __builtin_amdgcn_mfma_f32_16x16x32_bf16(
                            qa[it][ks_], kb, sacc[it][jt], 0, 0, 0);
                }
            }

            #pragma unroll
            for (int it=0; it<2; ++it)
                #pragma unroll
                for (int jt=0; jt<2; ++jt) {
                    const int jl = jt*16 + l15;
                    const int jg = j0 + jl;
                    #pragma unroll
                    for (int r=0; r<4; ++r) {
                        const int il = w32 + it*16 + quad*4 + r;
                        const float s = sacc[it][jt][r] + tab_s[il - jg + 255];
                        uint32_t hh, mm, ll;
                        split3(s, hh, mm, ll);
                        sh[0][il][jl] = (uint16_t)hh;
                        sh[1][il][jl] = (uint16_t)mm;
                        sh[2][il][jl] = (uint16_t)ll;
                    }
                }

            bf16x8 vb[3];
            #pragma unroll
            for (int dt=0; dt<3; ++dt)
                vb[dt] = *(const bf16x8*)&vT[dt*16 + l15][q8];
            #pragma unroll
            for (int it=0; it<2; ++it)
                #pragma unroll
                for (int p=0; p<3; ++p) {
                    const bf16x8 sa = *(const bf16x8*)&sh[p][w32 + it*16 + l15][q8];
                    #pragma unroll
                    for (int dt=0; dt<3; ++dt)
                        pacc[it][dt] = __builtin_amdgcn_mfma_f32_16x16x32_bf16(
                            sa, vb[dt], pacc[it][dt], 0, 0, 0);
                }
        }

        #pragma unroll
        for (int it=0; it<2; ++it)
            #pragma unroll
            for (int dt=0; dt<3; ++dt)
                #pragma unroll
                for (int r=0; r<4; ++r) {
                    const float xin = pacc[it][dt][r] * SCALE_F;
                    float v = vst[it][dt][r];
                    const float hh = v + (xin - v)*0.5f;
                    const uint16_t sp = (hh >= 1.0f) ? (uint16_t)0x3f80 : (uint16_t)0;
                    vst[it][dt][r] = (hh >= 1.0f) ? 0.f : hh;
                    const int ig = i0 + w32 + it*16 + quad*4 + r;
                    const int c  = h*D_ + dt*16 + l15;
                    as_[((size_t)(tb*N_ + ig))*C_ + c] = sp;
                }
    }
}

// ---------------------------------------------------------------------------
// K2.5: exact 3-way split of w_p (unchanged from round 2)
// ---------------------------------------------------------------------------
__global__ void k_wsplit(const float* __restrict__ wp,
                         uint16_t* __restrict__ wh, uint16_t* __restrict__ wm,
                         uint16_t* __restrict__ wl)
{
    const int idx = blockIdx.x*256 + threadIdx.x;
    uint32_t h, m, l;
    split3(wp[idx], h, m, l);
    wh[idx] = (uint16_t)h; wm[idx] = (uint16_t)m; wl[idx] = (uint16_t)l;
}

// ---------------------------------------------------------------------------
// K3: MFMA proj (unchanged from round 2 — verified)
// ---------------------------------------------------------------------------
__global__ __launch_bounds__(256, 2) void k_proj(
    const uint16_t* __restrict__ as_,
    const uint16_t* __restrict__ wh, const uint16_t* __restrict__ wm,
    const uint16_t* __restrict__ wl,
    const float* __restrict__ bnp, float* __restrict__ out)
{
    const int r0 = blockIdx.x * 64;
    const int c0 = blockIdx.y * 96;

    __shared__ __align__(16) uint16_t At[4][64][40];
    __shared__ __align__(16) uint16_t Bt[3][96][40];

    const int tid  = threadIdx.x;
    const int wv_  = tid >> 6;
    const int lane = tid & 63;
    const int l15  = lane & 15;
    const int quad = lane >> 4;
    const int q8   = quad * 8;

    f32x4 acc[4][6];
    #pragma unroll
    for (int t=0;t<4;++t)
        #pragma unroll
        for (int nt=0;nt<6;++nt) acc[t][nt] = (f32x4){0.f,0.f,0.f,0.f};

    for (int kstep=0; kstep<12; ++kstep) {
        const int k0 = kstep*32;
        __syncthreads();
        #pragma unroll
        for (int rep=0; rep<4; ++rep) {
            const int l = rep*256 + tid;
            const int t = l >> 8, row = (l >> 2) & 63, seg = l & 3;
            *(uint4*)&At[t][row][seg*8] =
                *(const uint4*)(as_ + ((size_t)(t*ROWS + r0 + row))*C_ + k0 + seg*8);
        }
        for (int l = tid; l < 1152; l += 256) {
            const int p = l / 384, rem = l - 384*p;
            const int c = rem >> 2, seg = rem & 3;
            const uint16_t* src = (p==0)? wh : (p==1)? wm : wl;
            *(uint4*)&Bt[p][c][seg*8] =
                *(const uint4*)(src + (size_t)(c0 + c)*C_ + k0 + seg*8);
        }
        __syncthreads();

        bf16x8 af[4];
        #pragma unroll
        for (int t=0;t<4;++t)
            af[t] = *(const bf16x8*)&At[t][wv_*16 + l15][q8];
        #pragma unroll
        for (int nt=0; nt<6; ++nt) {
            #pragma unroll
            for (int p=0; p<3; ++p) {
                const bf16x8 bf_ = *(const bf16x8*)&Bt[p][nt*16 + l15][q8];
                #pragma unroll
                for (int t=0;t<4;++t)
                    acc[t][nt] = __builtin_amdgcn_mfma_f32_16x16x32_bf16(
                        af[t], bf_, acc[t][nt], 0, 0, 0);
            }
        }
    }

    #pragma unroll
    for (int nt=0; nt<6; ++nt) {
        const int c = c0 + nt*16 + l15;
        const float g = bnp[c], be = bnp[C_+c], mu = bnp[2*C_+c], va = bnp[3*C_+c];
        const float scl = g * (float)(1.0 / sqrt((double)(va + 1e-5f)));
        #pragma unroll
        for (int r=0; r<4; ++r) {
            const int rg = r0 + wv_*16 + quad*4 + r;
            float v = 0.f;
            #pragma unroll
            for (int t=0; t<4; ++t) {
                const float y  = (acc[t][nt][r] - mu)*scl + be;
                const float hh = v + (y - v)*0.5f;
                const float sp = (hh >= 1.0f) ? 1.0f : 0.f;
                v = (hh >= 1.0f) ? 0.f : hh;
                out[((size_t)(t*ROWS + rg))*C_ + c] = sp;
            }
        }
    }
}

extern "C" void kernel_launch(void* const* d_in, const int* in_sizes, int n_in,
                              void* d_out, int out_size, void* d_ws, size_t ws_size,
                              hipStream_t stream) {
    const float* x   = (const float*)d_in[0];
    const float* wq  = (const float*)d_in[1];
    const float* wk  = (const float*)d_in[2];
    const float* wv  = (const float*)d_in[3];
    const float* wp  = (const float*)d_in[4];
    const float* bnq = (const float*)d_in[5];
    const float* bnk = (const float*)d_in[6];
    const float* bnv = (const float*)d_in[7];
    const float* bnp = (const float*)d_in[8];
    const float* rel = (const float*)d_in[9];
    float* out = (float*)d_out;
    uint8_t* ws = (uint8_t*)d_ws;
    uint16_t* qs  = (uint16_t*)(ws + QS_OFF);
    uint16_t* ks  = (uint16_t*)(ws + KS_OFF);
    uint16_t* vs  = (uint16_t*)(ws + VS_OFF);
    uint16_t* as_ = (uint16_t*)(ws + AS_OFF);
    uint16_t* wbr = (uint16_t*)(ws + AS_OFF);      // branch w-planes: dead once k_attn writes as_
    uint16_t* wh  = (uint16_t*)(ws + WH_OFF);
    uint16_t* wm  = (uint16_t*)(ws + WM_OFF);
    uint16_t* wl  = (uint16_t*)(ws + WL_OFF);

    k_wsplit3 <<<dim3(576, 3), 256, 0, stream>>>(wq, wk, wv, wbr);
    k_qkv_mfma<<<dim3(9, 256), 256, 0, stream>>>(x, wbr, bnq, bnk, bnv, qs, ks, vs);
    k_attn    <<<dim3(256, 2), 256, 0, stream>>>(qs, ks, vs, rel, as_);
    k_wsplit  <<<dim3(576),    256, 0, stream>>>(wp, wh, wm, wl);
    k_proj    <<<dim3(128, 4), 256, 0, stream>>>(as_, wh, wm, wl, bnp, out);
}

// Round 4
// 398.963 us; speedup vs baseline: 1.9170x; 1.0088x over previous
//
#include <hip/hip_runtime.h>
#include <stdint.h>

#define T_ 4
#define B_ 32
#define N_ 256
#define C_ 384
#define H_ 8
#define D_ 48
#define ROWS (B_*N_)                  // 8192 (b,n) rows
#define SCALE_F 0.051031036307982884f // 384^-0.5

// workspace layout (bytes); all spike tensors stored as bf16 (exact for {0,1})
#define QS_OFF 0u
#define KS_OFF 25165824u
#define VS_OFF 50331648u
#define AS_OFF 75497472u
#define WH_OFF 0u
#define WM_OFF 294912u
#define WL_OFF 589824u

typedef __bf16 bf16x8 __attribute__((ext_vector_type(8)));
typedef float  f32x4  __attribute__((ext_vector_type(4)));

__device__ __forceinline__ void split3(float s, uint32_t& h, uint32_t& m, uint32_t& l) {
    uint32_t u  = __float_as_uint(s);
    uint32_t hu = u & 0xffff0000u;
    float r1 = s - __uint_as_float(hu);
    uint32_t u1 = __float_as_uint(r1);
    uint32_t mu = u1 & 0xffff0000u;
    float r2 = r1 - __uint_as_float(mu);
    h = hu >> 16; m = mu >> 16; l = __float_as_uint(r2) >> 16;
}

// ---------------------------------------------------------------------------
// K0: exact 3-way split of w_q/w_k/w_v into bf16 planes (unchanged)
// ---------------------------------------------------------------------------
__global__ void k_wsplit3(const float* __restrict__ wq, const float* __restrict__ wk,
                          const float* __restrict__ wv, uint16_t* __restrict__ out)
{
    const int br = blockIdx.y;
    const float* __restrict__ w = (br==0)? wq : (br==1)? wk : wv;
    const int idx = blockIdx.x*256 + threadIdx.x;
    uint32_t h, m, l;
    split3(w[idx], h, m, l);
    uint16_t* base = out + (size_t)br*442368;
    base[idx] = (uint16_t)h;
    base[147456 + idx] = (uint16_t)m;
    base[294912 + idx] = (uint16_t)l;
}

#define SA 104   // LDS row stride (elems): 16B-aligned rows, even bank spread for b128

// ---------------------------------------------------------------------------
// K1 (primary): MFMA qkv GEMM + BN + LIF, M=256 tile (4t x 64 bn-rows), N=128.
// Dynamic LDS 79,872 B (At[256][104] + Bt[128][104]); 2 blocks/CU.
// Wave tile 128x64 (it=8, jt=4); B fragments held in VGPRs across it-loop.
// Numerically bit-identical to the round-3 kernel (same products, same order).
// ---------------------------------------------------------------------------
__global__ __launch_bounds__(256, 2) void k_qkv_mfma256(
    const float* __restrict__ x, const uint16_t* __restrict__ wbr,
    const float* __restrict__ bnq, const float* __restrict__ bnk, const float* __restrict__ bnv,
    uint16_t* __restrict__ qs, uint16_t* __restrict__ ks, uint16_t* __restrict__ vs)
{
    extern __shared__ uint16_t smem[];
    uint16_t (*At)[SA] = (uint16_t (*)[SA])smem;              // [256][104]
    uint16_t (*Bt)[SA] = (uint16_t (*)[SA])(smem + 256*SA);   // [128][104]

    const int cb = blockIdx.x;
    const int branch = cb / 3;
    const int ct = cb - branch*3;
    const int c0 = ct * 128;
    const int bn0 = blockIdx.y * 64;
    const float* __restrict__ bnp_ = (branch==0)? bnq : (branch==1)? bnk : bnv;
    uint16_t* __restrict__ outp = (branch==0)? qs : (branch==1)? ks : vs;
    const uint16_t* __restrict__ wpl = wbr + (size_t)branch*442368;

    const int tid  = threadIdx.x;
    const int wv   = tid >> 6;
    const int lane = tid & 63;
    const int l15  = lane & 15;
    const int quad = lane >> 4;
    const int q8   = quad * 8;
    const int rg   = wv >> 1;            // rg0 -> t0,t1 ; rg1 -> t2,t3
    const int wcol = (wv & 1) * 64;

    f32x4 acc[8][4];
    #pragma unroll
    for (int it=0; it<8; ++it)
        #pragma unroll
        for (int jt=0; jt<4; ++jt) acc[it][jt] = (f32x4){0.f,0.f,0.f,0.f};

    // A staging: thread -> M-row tid (t = tid>>6, bnl = tid&63), 32 k-elems
    const int tA = tid >> 6, bnlA = tid & 63;
    const float* xrow = x + ((size_t)(tA*ROWS + bn0 + bnlA))*C_;

    for (int kt=0; kt<12; ++kt) {
        const int k0 = kt*32;
        __syncthreads();
        {   // ---- A stage: 8 float4 loads, split3, 12 uint4 writes ----
            float fe[32];
            #pragma unroll
            for (int s=0; s<8; ++s)
                *(float4*)&fe[4*s] = *(const float4*)(xrow + k0 + 4*s);
            uint32_t hw[16], mw[16], lw[16];
            #pragma unroll
            for (int i=0; i<16; ++i) {
                const float s0 = fe[2*i], s1 = fe[2*i+1];
                const uint32_t h0 = __float_as_uint(s0) & 0xffff0000u;
                const uint32_t h1 = __float_as_uint(s1) & 0xffff0000u;
                const float r0 = s0 - __uint_as_float(h0);
                const float r1 = s1 - __uint_as_float(h1);
                const uint32_t m0 = __float_as_uint(r0) & 0xffff0000u;
                const uint32_t m1 = __float_as_uint(r1) & 0xffff0000u;
                const float p0 = r0 - __uint_as_float(m0);
                const float p1 = r1 - __uint_as_float(m1);
                hw[i] = (h0>>16) | h1;
                mw[i] = (m0>>16) | m1;
                lw[i] = (__float_as_uint(p0)>>16) | (__float_as_uint(p1) & 0xffff0000u);
            }
            #pragma unroll
            for (int s=0; s<4; ++s) {
                *(uint4*)&At[tid][     s*8] = make_uint4(hw[4*s],hw[4*s+1],hw[4*s+2],hw[4*s+3]);
                *(uint4*)&At[tid][32 + s*8] = make_uint4(mw[4*s],mw[4*s+1],mw[4*s+2],mw[4*s+3]);
                *(uint4*)&At[tid][64 + s*8] = make_uint4(lw[4*s],lw[4*s+1],lw[4*s+2],lw[4*s+3]);
            }
        }
        // ---- B stage: 3 planes x 128 c x 32 k = 1536 uint4 ----
        #pragma unroll
        for (int rep=0; rep<6; ++rep) {
            const int id = rep*256 + tid;
            const int p = id >> 9, rem = id & 511, c = rem >> 2, ks8 = rem & 3;
            *(uint4*)&Bt[c][p*32 + ks8*8] =
                *(const uint4*)(wpl + (size_t)p*147456 + (size_t)(c0 + c)*C_ + k0 + ks8*8);
        }
        __syncthreads();

        // ---- B fragments held in VGPRs; it-loop streams A fragments ----
        bf16x8 bfr[4][3];
        #pragma unroll
        for (int jt=0; jt<4; ++jt) {
            const uint16_t* bb = &Bt[wcol + jt*16 + l15][q8];
            bfr[jt][0] = *(const bf16x8*)(bb);
            bfr[jt][1] = *(const bf16x8*)(bb + 32);
            bfr[jt][2] = *(const bf16x8*)(bb + 64);
        }
        #pragma unroll
        for (int it=0; it<8; ++it) {
            const uint16_t* ar = &At[rg*128 + it*16 + l15][q8];
            const bf16x8 a0 = *(const bf16x8*)(ar);
            const bf16x8 a1 = *(const bf16x8*)(ar + 32);
            const bf16x8 a2 = *(const bf16x8*)(ar + 64);
            #pragma unroll
            for (int jt=0; jt<4; ++jt) {
                f32x4 a = acc[it][jt];
                a = __builtin_amdgcn_mfma_f32_16x16x32_bf16(a0, bfr[jt][0], a, 0,0,0);
                a = __builtin_amdgcn_mfma_f32_16x16x32_bf16(a0, bfr[jt][1], a, 0,0,0);
                a = __builtin_amdgcn_mfma_f32_16x16x32_bf16(a1, bfr[jt][0], a, 0,0,0);
                a = __builtin_amdgcn_mfma_f32_16x16x32_bf16(a0, bfr[jt][2], a, 0,0,0);
                a = __builtin_amdgcn_mfma_f32_16x16x32_bf16(a1, bfr[jt][1], a, 0,0,0);
                a = __builtin_amdgcn_mfma_f32_16x16x32_bf16(a2, bfr[jt][0], a, 0,0,0);
                acc[it][jt] = a;
            }
        }
    }

    // ---- epilogue: BN + LIF over t; rows = rg*128 + it*16 + quad*4 + r ->
    //      t = rg*2 + (it>>2), bnl = (it&3)*16 + quad*4 + r ----
    __syncthreads();
    float* vex = (float*)smem;    // [bnl 0..63][cl 0..127] f32 = 32 KB (At region dead)

    #define STORE_SP(tt, sp) do { \
        if (branch == 2) { \
            const int h2 = cg / 48, dd = cg - h2*48; \
            const int bng = bn0 + bnl; \
            outp[((((size_t)(tt)*B_ + (bng>>8))*H_ + h2)*D_ + dd)*N_ + (bng&255)] = (sp); \
        } else { \
            outp[((size_t)((tt)*ROWS + bn0 + bnl))*C_ + cg] = (sp); \
        } \
    } while(0)

    if (rg == 0) {
        #pragma unroll
        for (int jt=0; jt<4; ++jt) {
            const int cl = wcol + jt*16 + l15;
            const int cg = c0 + cl;
            const float g = bnp_[cg], be = bnp_[C_+cg], mu = bnp_[2*C_+cg], va = bnp_[3*C_+cg];
            const float scl = g * (float)(1.0 / sqrt((double)(va + 1e-5f)));
            #pragma unroll
            for (int a=0; a<4; ++a)
                #pragma unroll
                for (int r=0; r<4; ++r) {
                    const int bnl = a*16 + quad*4 + r;
                    const float y0 = (acc[a  ][jt][r] - mu)*scl + be;   // t0
                    const float y1 = (acc[4+a][jt][r] - mu)*scl + be;   // t1
                    float v = 0.f;
                    float h = v + (y0 - v)*0.5f;
                    STORE_SP(0, (h >= 1.0f) ? (uint16_t)0x3f80 : (uint16_t)0);
                    v = (h >= 1.0f) ? 0.f : h;
                    h = v + (y1 - v)*0.5f;
                    STORE_SP(1, (h >= 1.0f) ? (uint16_t)0x3f80 : (uint16_t)0);
                    v = (h >= 1.0f) ? 0.f : h;
                    vex[bnl*128 + cl] = v;
                }
        }
    }
    __syncthreads();
    if (rg == 1) {
        #pragma unroll
        for (int jt=0; jt<4; ++jt) {
            const int cl = wcol + jt*16 + l15;
            const int cg = c0 + cl;
            const float g = bnp_[cg], be = bnp_[C_+cg], mu = bnp_[2*C_+cg], va = bnp_[3*C_+cg];
            const float scl = g * (float)(1.0 / sqrt((double)(va + 1e-5f)));
            #pragma unroll
            for (int a=0; a<4; ++a)
                #pragma unroll
                for (int r=0; r<4; ++r) {
                    const int bnl = a*16 + quad*4 + r;
                    const float y2 = (acc[a  ][jt][r] - mu)*scl + be;   // t2
                    const float y3 = (acc[4+a][jt][r] - mu)*scl + be;   // t3
                    float v = vex[bnl*128 + cl];
                    float h = v + (y2 - v)*0.5f;
                    STORE_SP(2, (h >= 1.0f) ? (uint16_t)0x3f80 : (uint16_t)0);
                    v = (h >= 1.0f) ? 0.f : h;
                    h = v + (y3 - v)*0.5f;
                    STORE_SP(3, (h >= 1.0f) ? (uint16_t)0x3f80 : (uint16_t)0);
                }
        }
    }
    #undef STORE_SP
}

// ---------------------------------------------------------------------------
// K1 (fallback, round-3 verified): M=128 tile, static LDS
// ---------------------------------------------------------------------------
__global__ __launch_bounds__(256, 3) void k_qkv_mfma(
    const float* __restrict__ x, const uint16_t* __restrict__ wbr,
    const float* __restrict__ bnq, const float* __restrict__ bnk, const float* __restrict__ bnv,
    uint16_t* __restrict__ qs, uint16_t* __restrict__ ks, uint16_t* __restrict__ vs)
{
    const int cb = blockIdx.x;
    const int branch = cb / 3;
    const int ct = cb - branch*3;
    const int c0 = ct * 128;
    const int bn0 = blockIdx.y * 32;
    const float* __restrict__ bnp_ = (branch==0)? bnq : (branch==1)? bnk : bnv;
    uint16_t* __restrict__ outp = (branch==0)? qs : (branch==1)? ks : vs;
    const uint16_t* __restrict__ wpl = wbr + (size_t)branch*442368;

    __shared__ __align__(16) uint16_t At[128][104];
    __shared__ __align__(16) uint16_t Bt[128][104];

    const int tid  = threadIdx.x;
    const int wv   = tid >> 6;
    const int lane = tid & 63;
    const int l15  = lane & 15;
    const int quad = lane >> 4;
    const int q8   = quad * 8;
    const int rg   = wv >> 1;
    const int wcol = (wv & 1) * 64;

    f32x4 acc[4][4];
    #pragma unroll
    for (int it=0; it<4; ++it)
        #pragma unroll
        for (int jt=0; jt<4; ++jt) acc[it][jt] = (f32x4){0.f,0.f,0.f,0.f};

    const int trow = tid >> 1, half = tid & 1;
    const int tA = trow >> 5, bnlA = trow & 31;
    const float* xrow = x + ((size_t)(tA*ROWS + bn0 + bnlA))*C_ + half*16;

    for (int kt=0; kt<12; ++kt) {
        const int k0 = kt*32;
        __syncthreads();
        {
            float fe[16];
            #pragma unroll
            for (int s=0; s<4; ++s)
                *(float4*)&fe[4*s] = *(const float4*)(xrow + k0 + 4*s);
            uint32_t hw[8], mw[8], lw[8];
            #pragma unroll
            for (int i=0; i<8; ++i) {
                const float s0 = fe[2*i], s1 = fe[2*i+1];
                const uint32_t h0 = __float_as_uint(s0) & 0xffff0000u;
                const uint32_t h1 = __float_as_uint(s1) & 0xffff0000u;
                const float r0 = s0 - __uint_as_float(h0);
                const float r1 = s1 - __uint_as_float(h1);
                const uint32_t m0 = __float_as_uint(r0) & 0xffff0000u;
                const uint32_t m1 = __float_as_uint(r1) & 0xffff0000u;
                const float p0 = r0 - __uint_as_float(m0);
                const float p1 = r1 - __uint_as_float(m1);
                hw[i] = (h0>>16) | h1;
                mw[i] = (m0>>16) | m1;
                lw[i] = (__float_as_uint(p0)>>16) | (__float_as_uint(p1) & 0xffff0000u);
            }
            *(uint4*)&At[trow][ 0 + half*16]     = make_uint4(hw[0],hw[1],hw[2],hw[3]);
            *(uint4*)&At[trow][ 0 + half*16 + 8] = make_uint4(hw[4],hw[5],hw[6],hw[7]);
            *(uint4*)&At[trow][32 + half*16]     = make_uint4(mw[0],mw[1],mw[2],mw[3]);
            *(uint4*)&At[trow][32 + half*16 + 8] = make_uint4(mw[4],mw[5],mw[6],mw[7]);
            *(uint4*)&At[trow][64 + half*16]     = make_uint4(lw[0],lw[1],lw[2],lw[3]);
            *(uint4*)&At[trow][64 + half*16 + 8] = make_uint4(lw[4],lw[5],lw[6],lw[7]);
        }
        #pragma unroll
        for (int rep=0; rep<6; ++rep) {
            const int id = rep*256 + tid;
            const int p = id >> 9, rem = id & 511, c = rem >> 2, ks8 = rem & 3;
            *(uint4*)&Bt[c][p*32 + ks8*8] =
                *(const uint4*)(wpl + (size_t)p*147456 + (size_t)(c0 + c)*C_ + k0 + ks8*8);
        }
        __syncthreads();

        bf16x8 af[4][3];
        #pragma unroll
        for (int it=0; it<4; ++it) {
            const uint16_t* ar = &At[rg*64 + it*16 + l15][q8];
            af[it][0] = *(const bf16x8*)(ar);
            af[it][1] = *(const bf16x8*)(ar + 32);
            af[it][2] = *(const bf16x8*)(ar + 64);
        }
        #pragma unroll
        for (int jt=0; jt<4; ++jt) {
            const uint16_t* bb = &Bt[wcol + jt*16 + l15][q8];
            const bf16x8 b0 = *(const bf16x8*)(bb);
            const bf16x8 b1 = *(const bf16x8*)(bb + 32);
            const bf16x8 b2 = *(const bf16x8*)(bb + 64);
            #pragma unroll
            for (int it=0; it<4; ++it) {
                f32x4 a = acc[it][jt];
                a = __builtin_amdgcn_mfma_f32_16x16x32_bf16(af[it][0], b0, a, 0,0,0);
                a = __builtin_amdgcn_mfma_f32_16x16x32_bf16(af[it][0], b1, a, 0,0,0);
                a = __builtin_amdgcn_mfma_f32_16x16x32_bf16(af[it][1], b0, a, 0,0,0);
                a = __builtin_amdgcn_mfma_f32_16x16x32_bf16(af[it][0], b2, a, 0,0,0);
                a = __builtin_amdgcn_mfma_f32_16x16x32_bf16(af[it][1], b1, a, 0,0,0);
                a = __builtin_amdgcn_mfma_f32_16x16x32_bf16(af[it][2], b0, a, 0,0,0);
                acc[it][jt] = a;
            }
        }
    }

    __syncthreads();
    float* vex = (float*)&At[0][0];

    #define STORE_SP(tt, sp) do { \
        if (branch == 2) { \
            const int h2 = cg / 48, dd = cg - h2*48; \
            const int bng = bn0 + bnl; \
            outp[((((size_t)(tt)*B_ + (bng>>8))*H_ + h2)*D_ + dd)*N_ + (bng&255)] = (sp); \
        } else { \
            outp[((size_t)((tt)*ROWS + bn0 + bnl))*C_ + cg] = (sp); \
        } \
    } while(0)

    if (rg == 0) {
        #pragma unroll
        for (int jt=0; jt<4; ++jt) {
            const int cl = wcol + jt*16 + l15;
            const int cg = c0 + cl;
            const float g = bnp_[cg], be = bnp_[C_+cg], mu = bnp_[2*C_+cg], va = bnp_[3*C_+cg];
            const float scl = g * (float)(1.0 / sqrt((double)(va + 1e-5f)));
            #pragma unroll
            for (int a=0; a<2; ++a)
                #pragma unroll
                for (int r=0; r<4; ++r) {
                    const int bnl = a*16 + quad*4 + r;
                    const float y0 = (acc[a  ][jt][r] - mu)*scl + be;
                    const float y1 = (acc[a+2][jt][r] - mu)*scl + be;
                    float v = 0.f;
                    float h = v + (y0 - v)*0.5f;
                    STORE_SP(0, (h >= 1.0f) ? (uint16_t)0x3f80 : (uint16_t)0);
                    v = (h >= 1.0f) ? 0.f : h;
                    h = v + (y1 - v)*0.5f;
                    STORE_SP(1, (h >= 1.0f) ? (uint16_t)0x3f80 : (uint16_t)0);
                    v = (h >= 1.0f) ? 0.f : h;
                    vex[bnl*128 + cl] = v;
                }
        }
    }
    __syncthreads();
    if (rg == 1) {
        #pragma unroll
        for (int jt=0; jt<4; ++jt) {
            const int cl = wcol + jt*16 + l15;
            const int cg = c0 + cl;
            const float g = bnp_[cg], be = bnp_[C_+cg], mu = bnp_[2*C_+cg], va = bnp_[3*C_+cg];
            const float scl = g * (float)(1.0 / sqrt((double)(va + 1e-5f)));
            #pragma unroll
            for (int a=0; a<2; ++a)
                #pragma unroll
                for (int r=0; r<4; ++r) {
                    const int bnl = a*16 + quad*4 + r;
                    const float y2 = (acc[a  ][jt][r] - mu)*scl + be;
                    const float y3 = (acc[a+2][jt][r] - mu)*scl + be;
                    float v = vex[bnl*128 + cl];
                    float h = v + (y2 - v)*0.5f;
                    STORE_SP(2, (h >= 1.0f) ? (uint16_t)0x3f80 : (uint16_t)0);
                    v = (h >= 1.0f) ? 0.f : h;
                    h = v + (y3 - v)*0.5f;
                    STORE_SP(3, (h >= 1.0f) ? (uint16_t)0x3f80 : (uint16_t)0);
                }
        }
    }
    #undef STORE_SP
}

// ---------------------------------------------------------------------------
// K2: MFMA attention + attn-LIF (unchanged — verified)
// ---------------------------------------------------------------------------
__global__ __launch_bounds__(256, 2) void k_attn(
    const uint16_t* __restrict__ qs, const uint16_t* __restrict__ ks, const uint16_t* __restrict__ vs,
    const float* __restrict__ rel, uint16_t* __restrict__ as_)
{
    const int bh = blockIdx.x;
    const int b = bh >> 3, h = bh & 7;
    const int i0 = blockIdx.y * 128;

    __shared__ __align__(16) uint16_t qt[128][72];
    __shared__ __align__(16) uint16_t kt[32][72];
    __shared__ __align__(16) uint16_t vT[48][40];
    __shared__ __align__(16) uint16_t sh[3][128][40];
    __shared__ float tab_s[384];

    const int tid  = threadIdx.x;
    const int wv_  = tid >> 6;
    const int lane = tid & 63;
    const int l15  = lane & 15;
    const int quad = lane >> 4;
    const int w32  = wv_ * 32;
    const int q8   = quad * 8;

    for (int l = tid; l < 383; l += 256) tab_s[l] = rel[(size_t)(i0 + l)*H_ + h];
    {
        const uint4 z = make_uint4(0,0,0,0);
        { const int row = tid >> 1, seg = tid & 1;
          *(uint4*)&qt[row][48 + seg*8] = z; }
        if (tid < 64) { const int row = tid >> 1, seg = tid & 1;
          *(uint4*)&kt[row][48 + seg*8] = z; }
    }

    float vst[2][3][4];
    #pragma unroll
    for (int a=0;a<2;++a)
        #pragma unroll
        for (int e=0;e<3;++e)
            #pragma unroll
            for (int r=0;r<4;++r) vst[a][e][r]=0.f;

    for (int t=0; t<4; ++t) {
        const int tb = t*B_ + b;
        __syncthreads();
        #pragma unroll
        for (int rep=0; rep<3; ++rep) {
            const int l = rep*256 + tid;
            const int row = l / 6, seg = l - 6*row;
            *(uint4*)&qt[row][seg*8] =
                *(const uint4*)(qs + ((size_t)(tb*N_ + i0 + row))*C_ + h*D_ + seg*8);
        }

        f32x4 pacc[2][3];
        #pragma unroll
        for (int a=0;a<2;++a)
            #pragma unroll
            for (int e=0;e<3;++e) pacc[a][e] = (f32x4){0.f,0.f,0.f,0.f};

        for (int j0 = 0; j0 < 256; j0 += 32) {
            __syncthreads();
            if (tid < 192) {
                const int row = tid / 6, seg = tid - 6*row;
                *(uint4*)&kt[row][seg*8] =
                    *(const uint4*)(ks + ((size_t)(tb*N_ + j0 + row))*C_ + h*D_ + seg*8);
            } else {
                const int l = tid - 192;
                #pragma unroll
                for (int rep=0; rep<3; ++rep) {
                    const int e = rep*64 + l;
                    const int d = e >> 2, seg = e & 3;
                    *(uint4*)&vT[d][seg*8] =
                        *(const uint4*)(vs + (((size_t)(tb*H_ + h))*D_ + d)*N_ + j0 + seg*8);
                }
            }
            __syncthreads();

            f32x4 sacc[2][2];
            #pragma unroll
            for (int a=0;a<2;++a)
                #pragma unroll
                for (int c2=0;c2<2;++c2) sacc[a][c2] = (f32x4){0.f,0.f,0.f,0.f};
            bf16x8 qa[2][2];
            #pragma unroll
            for (int it=0; it<2; ++it)
                #pragma unroll
                for (int ks_=0; ks_<2; ++ks_)
                    qa[it][ks_] = *(const bf16x8*)&qt[w32 + it*16 + l15][ks_*32 + q8];
            #pragma unroll
            for (int jt=0; jt<2; ++jt) {
                #pragma unroll
                for (int ks_=0; ks_<2; ++ks_) {
                    const bf16x8 kb = *(const bf16x8*)&kt[jt*16 + l15][ks_*32 + q8];
                    #pragma unroll
                    for (int it=0; it<2; ++it)
                        sacc[it][jt] = __builtin_amdgcn_mfma_f32_16x16x32_bf16(
                            qa[it][ks_], kb, sacc[it][jt], 0, 0, 0);
                }
            }

            #pragma unroll
            for (int it=0; it<2; ++it)
                #pragma unroll
                for (int jt=0; jt<2; ++jt) {
                    const int jl = jt*16 + l15;
                    const int jg = j0 + jl;
                    #pragma unroll
                    for (int r=0; r<4; ++r) {
                        const int il = w32 + it*16 + quad*4 + r;
                        const float s = sacc[it][jt][r] + tab_s[il - jg + 255];
                        uint32_t hh, mm, ll;
                        split3(s, hh, mm, ll);
                        sh[0][il][jl] = (uint16_t)hh;
                        sh[1][il][jl] = (uint16_t)mm;
                        sh[2][il][jl] = (uint16_t)ll;
                    }
                }

            bf16x8 vb[3];
            #pragma unroll
            for (int dt=0; dt<3; ++dt)
                vb[dt] = *(const bf16x8*)&vT[dt*16 + l15][q8];
            #pragma unroll
            for (int it=0; it<2; ++it)
                #pragma unroll
                for (int p=0; p<3; ++p) {
                    const bf16x8 sa = *(const bf16x8*)&sh[p][w32 + it*16 + l15][q8];
                    #pragma unroll
                    for (int dt=0; dt<3; ++dt)
                        pacc[it][dt] = __builtin_amdgcn_mfma_f32_16x16x32_bf16(
                            sa, vb[dt], pacc[it][dt], 0, 0, 0);
                }
        }

        #pragma unroll
        for (int it=0; it<2; ++it)
            #pragma unroll
            for (int dt=0; dt<3; ++dt)
                #pragma unroll
                for (int r=0; r<4; ++r) {
                    const float xin = pacc[it][dt][r] * SCALE_F;
                    float v = vst[it][dt][r];
                    const float hh = v + (xin - v)*0.5f;
                    const uint16_t sp = (hh >= 1.0f) ? (uint16_t)0x3f80 : (uint16_t)0;
                    vst[it][dt][r] = (hh >= 1.0f) ? 0.f : hh;
                    const int ig = i0 + w32 + it*16 + quad*4 + r;
                    const int c  = h*D_ + dt*16 + l15;
                    as_[((size_t)(tb*N_ + ig))*C_ + c] = sp;
                }
    }
}

// ---------------------------------------------------------------------------
// K2.5: exact 3-way split of w_p (unchanged)
// ---------------------------------------------------------------------------
__global__ void k_wsplit(const float* __restrict__ wp,
                         uint16_t* __restrict__ wh, uint16_t* __restrict__ wm,
                         uint16_t* __restrict__ wl)
{
    const int idx = blockIdx.x*256 + threadIdx.x;
    uint32_t h, m, l;
    split3(wp[idx], h, m, l);
    wh[idx] = (uint16_t)h; wm[idx] = (uint16_t)m; wl[idx] = (uint16_t)l;
}

// ---------------------------------------------------------------------------
// K3: MFMA proj (unchanged — verified)
// ---------------------------------------------------------------------------
__global__ __launch_bounds__(256, 2) void k_proj(
    const uint16_t* __restrict__ as_,
    const uint16_t* __restrict__ wh, const uint16_t* __restrict__ wm,
    const uint16_t* __restrict__ wl,
    const float* __restrict__ bnp, float* __restrict__ out)
{
    const int r0 = blockIdx.x * 64;
    const int c0 = blockIdx.y * 96;

    __shared__ __align__(16) uint16_t At[4][64][40];
    __shared__ __align__(16) uint16_t Bt[3][96][40];

    const int tid  = threadIdx.x;
    const int wv_  = tid >> 6;
    const int lane = tid & 63;
    const int l15  = lane & 15;
    const int quad = lane >> 4;
    const int q8   = quad * 8;

    f32x4 acc[4][6];
    #pragma unroll
    for (int t=0;t<4;++t)
        #pragma unroll
        for (int nt=0;nt<6;++nt) acc[t][nt] = (f32x4){0.f,0.f,0.f,0.f};

    for (int kstep=0; kstep<12; ++kstep) {
        const int k0 = kstep*32;
        __syncthreads();
        #pragma unroll
        for (int rep=0; rep<4; ++rep) {
            const int l = rep*256 + tid;
            const int t = l >> 8, row = (l >> 2) & 63, seg = l & 3;
            *(uint4*)&At[t][row][seg*8] =
                *(const uint4*)(as_ + ((size_t)(t*ROWS + r0 + row))*C_ + k0 + seg*8);
        }
        for (int l = tid; l < 1152; l += 256) {
            const int p = l / 384, rem = l - 384*p;
            const int c = rem >> 2, seg = rem & 3;
            const uint16_t* src = (p==0)? wh : (p==1)? wm : wl;
            *(uint4*)&Bt[p][c][seg*8] =
                *(const uint4*)(src + (size_t)(c0 + c)*C_ + k0 + seg*8);
        }
        __syncthreads();

        bf16x8 af[4];
        #pragma unroll
        for (int t=0;t<4;++t)
            af[t] = *(const bf16x8*)&At[t][wv_*16 + l15][q8];
        #pragma unroll
        for (int nt=0; nt<6; ++nt) {
            #pragma unroll
            for (int p=0; p<3; ++p) {
                const bf16x8 bf_ = *(const bf16x8*)&Bt[p][nt*16 + l15][q8];
                #pragma unroll
                for (int t=0;t<4;++t)
                    acc[t][nt] = __builtin_amdgcn_mfma_f32_16x16x32_bf16(
                        af[t], bf_, acc[t][nt], 0, 0, 0);
            }
        }
    }

    #pragma unroll
    for (int nt=0; nt<6; ++nt) {
        const int c = c0 + nt*16 + l15;
        const float g = bnp[c], be = bnp[C_+c], mu = bnp[2*C_+c], va = bnp[3*C_+c];
        const float scl = g * (float)(1.0 / sqrt((double)(va + 1e-5f)));
        #pragma unroll
        for (int r=0; r<4; ++r) {
            const int rg = r0 + wv_*16 + quad*4 + r;
            float v = 0.f;
            #pragma unroll
            for (int t=0; t<4; ++t) {
                const float y  = (acc[t][nt][r] - mu)*scl + be;
                const float hh = v + (y - v)*0.5f;
                const float sp = (hh >= 1.0f) ? 1.0f : 0.f;
                v = (hh >= 1.0f) ? 0.f : hh;
                out[((size_t)(t*ROWS + rg))*C_ + c] = sp;
            }
        }
    }
}

// ---------------------------------------------------------------------------
// static-init (runs at dlopen, OUTSIDE graph capture): opt the M=256 kernel
// into >64KB dynamic LDS. If it fails, kernel_launch uses the M=128 fallback.
// ---------------------------------------------------------------------------
#define QKV256_LDS_BYTES ((256 + 128) * SA * 2)   // 79,872
struct BigLdsInit {
    bool ok;
    BigLdsInit() {
        ok = (hipFuncSetAttribute((const void*)k_qkv_mfma256,
                                  hipFuncAttributeMaxDynamicSharedMemorySize,
                                  QKV256_LDS_BYTES) == hipSuccess);
    }
};
static BigLdsInit g_biglds;

extern "C" void kernel_launch(void* const* d_in, const int* in_sizes, int n_in,
                              void* d_out, int out_size, void* d_ws, size_t ws_size,
                              hipStream_t stream) {
    const float* x   = (const float*)d_in[0];
    const float* wq  = (const float*)d_in[1];
    const float* wk  = (const float*)d_in[2];
    const float* wv  = (const float*)d_in[3];
    const float* wp  = (const float*)d_in[4];
    const float* bnq = (const float*)d_in[5];
    const float* bnk = (const float*)d_in[6];
    const float* bnv = (const float*)d_in[7];
    const float* bnp = (const float*)d_in[8];
    const float* rel = (const float*)d_in[9];
    float* out = (float*)d_out;
    uint8_t* ws = (uint8_t*)d_ws;
    uint16_t* qs  = (uint16_t*)(ws + QS_OFF);
    uint16_t* ks  = (uint16_t*)(ws + KS_OFF);
    uint16_t* vs  = (uint16_t*)(ws + VS_OFF);
    uint16_t* as_ = (uint16_t*)(ws + AS_OFF);
    uint16_t* wbr = (uint16_t*)(ws + AS_OFF);
    uint16_t* wh  = (uint16_t*)(ws + WH_OFF);
    uint16_t* wm  = (uint16_t*)(ws + WM_OFF);
    uint16_t* wl  = (uint16_t*)(ws + WL_OFF);

    k_wsplit3 <<<dim3(576, 3), 256, 0, stream>>>(wq, wk, wv, wbr);
    if (g_biglds.ok) {
        k_qkv_mfma256<<<dim3(9, 128), 256, QKV256_LDS_BYTES, stream>>>(
            x, wbr, bnq, bnk, bnv, qs, ks, vs);
    } else {
        k_qkv_mfma<<<dim3(9, 256), 256, 0, stream>>>(x, wbr, bnq, bnk, bnv, qs, ks, vs);
    }
    k_attn    <<<dim3(256, 2), 256, 0, stream>>>(qs, ks, vs, rel, as_);
    k_wsplit  <<<dim3(576),    256, 0, stream>>>(wp, wh, wm, wl);
    k_proj    <<<dim3(128, 4), 256, 0, stream>>>(as_, wh, wm, wl, bnp, out);
}